// Round 1
// baseline (1324.017 us; speedup 1.0000x reference)
//
#include <hip/hip_runtime.h>

// MoE_77644418777543 — round 0: fp32 sparse (top-4) grouped-GEMM baseline.
// B=4096, D=512, H=1024, E=16, K_TOP=4, C=20.
// Workspace layout (floats), ~143 MB total (aliased by liveness):
//   combined  [4096*512]          @ 0
//   h1        [16384*1024]        @ 2,097,152   (later reused: fused @ same, o @ +4,194,304)
//   gbuf/h2   [16384*1024]        @ 18,874,368  (g uses first 4096*1024; h2 overwrites after g dead)
//   wq        [16384]             @ 35,651,584
//   rows      [16*4096] (int)     @ 35,667,968
//   counts    [16]      (int)     @ 35,733,504

#define EPSN 1e-5f

__device__ __forceinline__ float gelu_f(float x) {
    return 0.5f * x * (1.0f + erff(x * 0.70710678118654752440f));
}

__global__ __launch_bounds__(256) void concat_kernel(const float4* __restrict__ wifi,
                                                     const float4* __restrict__ rfid,
                                                     float4* __restrict__ comb) {
    int gid = blockIdx.x * 256 + threadIdx.x;   // 4096 * 128
    int b = gid >> 7, c = gid & 127;
    comb[gid] = (c < 64) ? wifi[b * 64 + c] : rfid[b * 64 + (c - 64)];
}

// Generic 64x64 tile fp32 GEMM, BK=16, 256 threads, 4x4 per thread.
// EPI: 0 = +bias only; 1 = +bias, BN(eval), GELU.
// GATHER: A rows and output rows come from per-expert packed lists (packed = b*4+k);
//         ASHIFT: A row = packed >> ASHIFT (2 for reading combined, 0 for reading h1).
template<int EPI, int ASHIFT, bool GATHER>
__global__ __launch_bounds__(256) void gemm64(
    const float* __restrict__ A, int lda,
    const float* __restrict__ W, long wstride,
    const float* __restrict__ bias,
    const float* __restrict__ bng, const float* __restrict__ bnb,
    const float* __restrict__ bnm, const float* __restrict__ bnv,
    int pstride,
    float* __restrict__ out, int ldo,
    const int* __restrict__ rows, const int* __restrict__ counts,
    int M, int N, int K)
{
    const int e  = blockIdx.z;
    const int m0 = blockIdx.y << 6;
    const int n0 = blockIdx.x << 6;
    const int cnt = GATHER ? counts[e] : M;
    if (m0 >= cnt) return;

    __shared__ float As[16][68];   // [k][m], pad 68 -> 16B-aligned float4 rows, 2-way banks (free)
    __shared__ float Bs[16][68];   // [k][n]
    __shared__ int rid[64];
    __shared__ int ain[64];

    const int tid = threadIdx.x;
    if (tid < 64) {
        int i = m0 + tid;
        if (GATHER) {
            if (i < cnt) {
                int packed = rows[e * 4096 + i];
                rid[tid] = packed;
                ain[tid] = packed >> ASHIFT;
            } else { rid[tid] = -1; ain[tid] = 0; }
        } else {
            rid[tid] = i; ain[tid] = i;
        }
    }
    __syncthreads();

    const float* We = W + (long)e * wstride + n0;
    const int ty = tid >> 4, tx = tid & 15;

    // staging maps
    const int arow = tid >> 2;              // 0..63 (m)
    const int akq  = (tid & 3) << 2;        // 0,4,8,12 (k)
    const float* Aptr = A + (long)ain[arow] * lda + akq;
    const int bkr = tid >> 4;               // 0..15 (k)
    const int bnq = (tid & 15) << 2;        // 0..60 (n)
    const float* Bptr = We + (long)bkr * N + bnq;

    float acc[4][4] = {};

    for (int k0 = 0; k0 < K; k0 += 16) {
        float4 av = *(const float4*)(Aptr + k0);
        float4 bv = *(const float4*)(Bptr + (long)k0 * N);
        As[akq + 0][arow] = av.x;
        As[akq + 1][arow] = av.y;
        As[akq + 2][arow] = av.z;
        As[akq + 3][arow] = av.w;
        *(float4*)&Bs[bkr][bnq] = bv;
        __syncthreads();
#pragma unroll
        for (int kk = 0; kk < 16; ++kk) {
            float4 af = *(const float4*)&As[kk][ty << 2];
            float4 bf = *(const float4*)&Bs[kk][tx << 2];
            const float a4[4] = {af.x, af.y, af.z, af.w};
            const float b4[4] = {bf.x, bf.y, bf.z, bf.w};
#pragma unroll
            for (int i = 0; i < 4; ++i)
#pragma unroll
                for (int j = 0; j < 4; ++j)
                    acc[i][j] += a4[i] * b4[j];
        }
        __syncthreads();
    }

#pragma unroll
    for (int i = 0; i < 4; ++i) {
        int r = (ty << 2) + i;
        int orow = rid[r];
        if (orow < 0) continue;
        int c0 = n0 + (tx << 2);
        float4 v;
        float* vp = &v.x;
#pragma unroll
        for (int j = 0; j < 4; ++j) {
            int c = c0 + j;
            int pc = e * pstride + c;
            float x = acc[i][j] + bias[pc];
            if (EPI == 1) {
                float s = bng[pc] * rsqrtf(bnv[pc] + EPSN);
                x = (x - bnm[pc]) * s + bnb[pc];
                x = gelu_f(x);
            }
            vp[j] = x;
        }
        *(float4*)(out + (long)orow * ldo + c0) = v;
    }
}

__global__ __launch_bounds__(256) void ln_gelu_kernel(float* __restrict__ g,
                                                      const float* __restrict__ lng,
                                                      const float* __restrict__ lnb) {
    int b = blockIdx.x;
    int tid = threadIdx.x;
    int c = tid << 2;
    float4 v = *(const float4*)(g + (long)b * 1024 + c);
    float s = v.x + v.y + v.z + v.w;
    float q = v.x * v.x + v.y * v.y + v.z * v.z + v.w * v.w;
    for (int off = 32; off > 0; off >>= 1) {
        s += __shfl_down(s, off);
        q += __shfl_down(q, off);
    }
    __shared__ float rs[4], rq[4];
    int wid = tid >> 6;
    if ((tid & 63) == 0) { rs[wid] = s; rq[wid] = q; }
    __syncthreads();
    float S = rs[0] + rs[1] + rs[2] + rs[3];
    float Q = rq[0] + rq[1] + rq[2] + rq[3];
    float mu = S * (1.0f / 1024.0f);
    float var = Q * (1.0f / 1024.0f) - mu * mu;
    float rstd = rsqrtf(var + EPSN);
    float4 o;
    o.x = gelu_f((v.x - mu) * rstd * lng[c + 0] + lnb[c + 0]);
    o.y = gelu_f((v.y - mu) * rstd * lng[c + 1] + lnb[c + 1]);
    o.z = gelu_f((v.z - mu) * rstd * lng[c + 2] + lnb[c + 2]);
    o.w = gelu_f((v.w - mu) * rstd * lng[c + 3] + lnb[c + 3]);
    *(float4*)(g + (long)b * 1024 + c) = o;
}

__global__ __launch_bounds__(256) void gate_topk_kernel(
    const float* __restrict__ g, const float* __restrict__ w2, const float* __restrict__ b2,
    float* __restrict__ wout, int* __restrict__ rows, int* __restrict__ counts)
{
    int b = blockIdx.x;
    int tid = threadIdx.x;
    int e = tid & 15, chunk = tid >> 4;    // 16 chunks x 64 elems
    const float* gr = g + (long)b * 1024;
    float p = 0.f;
    for (int i = 0; i < 64; ++i) {
        int idx = chunk * 64 + i;
        p += gr[idx] * w2[idx * 16 + e];
    }
    __shared__ float red[16][17];
    red[chunk][e] = p;
    __syncthreads();
    __shared__ float logit[16];
    if (tid < 16) {
        float s = b2[tid];
        for (int c = 0; c < 16; ++c) s += red[c][tid];
        logit[tid] = s;
    }
    __syncthreads();
    if (tid == 0) {
        float m = logit[0];
        for (int i = 1; i < 16; ++i) m = fmaxf(m, logit[i]);
        float p16[16]; float Z = 0.f;
        for (int i = 0; i < 16; ++i) { p16[i] = __expf(logit[i] - m); Z += p16[i]; }
        // exact expf for safety (match np within fp32 noise)
        Z = 0.f;
        for (int i = 0; i < 16; ++i) { p16[i] = expf(logit[i] - m); }
        for (int i = 0; i < 16; ++i) Z += p16[i];
        float inv = 1.0f / Z;
        for (int i = 0; i < 16; ++i) p16[i] *= inv;
        int idx4[4]; float v4[4];
        bool used[16] = {};
        for (int k = 0; k < 4; ++k) {
            int bi = 0; float bv = -1.f;
            for (int i = 0; i < 16; ++i)
                if (!used[i] && p16[i] > bv) { bv = p16[i]; bi = i; }
            used[bi] = true; idx4[k] = bi; v4[k] = bv;
        }
        float q[4]; float Z2 = 0.f;
        for (int k = 0; k < 4; ++k) { q[k] = expf(v4[k] - v4[0]); Z2 += q[k]; }
        float inv2 = 1.0f / Z2;
        for (int k = 0; k < 4; ++k) {
            wout[b * 4 + k] = q[k] * inv2;
            int ee = idx4[k];
            int j = atomicAdd(&counts[ee], 1);
            rows[ee * 4096 + j] = (b << 2) | k;
        }
    }
}

__global__ __launch_bounds__(256) void combine_kernel(const float4* __restrict__ h2,
                                                      const float* __restrict__ w,
                                                      float4* __restrict__ fused) {
    int gid = blockIdx.x * 256 + threadIdx.x;  // 4096*256
    int b = gid >> 8, c = gid & 255;
    float4 acc = {0.f, 0.f, 0.f, 0.f};
#pragma unroll
    for (int k = 0; k < 4; ++k) {
        float wk = w[b * 4 + k];
        float4 v = h2[(long)(b * 4 + k) * 256 + c];
        acc.x += wk * v.x; acc.y += wk * v.y; acc.z += wk * v.z; acc.w += wk * v.w;
    }
    fused[gid] = acc;
}

__global__ __launch_bounds__(256) void fin2_kernel(const float* __restrict__ o,
                                                   const float* __restrict__ w2,
                                                   const float* __restrict__ b2,
                                                   float* __restrict__ out) {
    __shared__ float ws[512 * 20];
    int tid = threadIdx.x;
    for (int i = tid; i < 512 * 20; i += 256) ws[i] = w2[i];
    __syncthreads();
    int r = blockIdx.x * 64 + (tid >> 2);
    int c0 = (tid & 3) * 5;
    float acc[5];
#pragma unroll
    for (int j = 0; j < 5; ++j) acc[j] = b2[c0 + j];
    const float* orow = o + (long)r * 512;
    for (int i = 0; i < 512; ++i) {
        float v = orow[i];
#pragma unroll
        for (int j = 0; j < 5; ++j) acc[j] += v * ws[i * 20 + c0 + j];
    }
#pragma unroll
    for (int j = 0; j < 5; ++j) out[r * 20 + c0 + j] = acc[j];
}

extern "C" void kernel_launch(void* const* d_in, const int* in_sizes, int n_in,
                              void* d_out, int out_size, void* d_ws, size_t ws_size,
                              hipStream_t stream) {
    const float* wifi    = (const float*)d_in[0];
    const float* rfid    = (const float*)d_in[1];
    const float* gate_w1 = (const float*)d_in[2];
    const float* gate_b1 = (const float*)d_in[3];
    const float* gln_g   = (const float*)d_in[4];
    const float* gln_b   = (const float*)d_in[5];
    const float* gate_w2 = (const float*)d_in[6];
    const float* gate_b2 = (const float*)d_in[7];
    const float* exp_w1  = (const float*)d_in[8];
    const float* exp_b1  = (const float*)d_in[9];
    const float* bn1g    = (const float*)d_in[10];
    const float* bn1b    = (const float*)d_in[11];
    const float* bn1m    = (const float*)d_in[12];
    const float* bn1v    = (const float*)d_in[13];
    const float* exp_w2  = (const float*)d_in[14];
    const float* exp_b2  = (const float*)d_in[15];
    const float* bn2g    = (const float*)d_in[16];
    const float* bn2b    = (const float*)d_in[17];
    const float* bn2m    = (const float*)d_in[18];
    const float* bn2v    = (const float*)d_in[19];
    const float* fin_w1  = (const float*)d_in[20];
    const float* fin_b1  = (const float*)d_in[21];
    const float* fbng    = (const float*)d_in[22];
    const float* fbnb    = (const float*)d_in[23];
    const float* fbnm    = (const float*)d_in[24];
    const float* fbnv    = (const float*)d_in[25];
    const float* fin_w2  = (const float*)d_in[26];
    const float* fin_b2  = (const float*)d_in[27];
    float* out = (float*)d_out;

    float* ws       = (float*)d_ws;
    float* combined = ws;                     // 4096*512
    float* h1       = ws + 2097152;           // 16384*1024
    float* fused    = h1;                     // alias: h1 dead when written
    float* o        = h1 + 4194304;           // alias: within old h1
    float* gbuf     = ws + 18874368;          // 4096*1024 (gate hidden)
    float* h2       = gbuf;                   // alias: g dead when written
    float* wq       = ws + 35651584;          // 16384
    int*   rows     = (int*)(ws + 35667968);  // 16*4096
    int*   counts   = (int*)(ws + 35733504);  // 16

    hipMemsetAsync(counts, 0, 16 * sizeof(int), stream);

    concat_kernel<<<2048, 256, 0, stream>>>((const float4*)wifi, (const float4*)rfid,
                                            (float4*)combined);

    // gate GEMM1: [4096,512] @ [512,1024] + b  -> gbuf
    gemm64<0, 0, false><<<dim3(16, 64, 1), 256, 0, stream>>>(
        combined, 512, gate_w1, 0, gate_b1,
        nullptr, nullptr, nullptr, nullptr, 0,
        gbuf, 1024, nullptr, nullptr, 4096, 1024, 512);

    ln_gelu_kernel<<<4096, 256, 0, stream>>>(gbuf, gln_g, gln_b);

    gate_topk_kernel<<<4096, 256, 0, stream>>>(gbuf, gate_w2, gate_b2, wq, rows, counts);

    // expert GEMM1 (sparse, gathered): combined rows -> h1[b*4+k]
    gemm64<1, 2, true><<<dim3(16, 64, 16), 256, 0, stream>>>(
        combined, 512, exp_w1, (long)512 * 1024, exp_b1,
        bn1g, bn1b, bn1m, bn1v, 1024,
        h1, 1024, rows, counts, 4096, 1024, 512);

    // expert GEMM2 (sparse): h1[b*4+k] -> h2[b*4+k]  (overwrites gbuf, g dead)
    gemm64<1, 0, true><<<dim3(16, 64, 16), 256, 0, stream>>>(
        h1, 1024, exp_w2, (long)1024 * 1024, exp_b2,
        bn2g, bn2b, bn2m, bn2v, 1024,
        h2, 1024, rows, counts, 4096, 1024, 1024);

    combine_kernel<<<4096, 256, 0, stream>>>((const float4*)h2, wq, (float4*)fused);

    // final GEMM1: [4096,1024] @ [1024,512], BN+GELU -> o
    gemm64<1, 0, false><<<dim3(8, 64, 1), 256, 0, stream>>>(
        fused, 1024, fin_w1, 0, fin_b1,
        fbng, fbnb, fbnm, fbnv, 0,
        o, 512, nullptr, nullptr, 4096, 512, 1024);

    fin2_kernel<<<64, 256, 0, stream>>>(o, fin_w2, fin_b2, out);
}

// Round 2
// 700.729 us; speedup vs baseline: 1.8895x; 1.8895x over previous
//
#include <hip/hip_runtime.h>

// MoE_77644418777543 — round 1: bf16 MFMA for expert GEMMs + final GEMM1.
// B=4096, D=512, H=1024, E=16, K_TOP=4, C=20.
// Gate path kept fp32 (top-4 selection stability). Expert GEMM1/GEMM2 and
// fin1 use mfma_f32_16x16x32_bf16, 128x128x32 tiles, global_load_lds(16B),
// pre-transposed bf16 weights [n][k] so A and B frags are ds_read_b128.
//
// Workspace (bytes, MB = 2^20), ~131 MB peak, aliased by liveness:
//   0-8M    combined fp32            (gate gemm + cvt; then dead)
//   8-12M   cbf bf16                 (dead after expert GEMM1)
//   12-28M  w1t bf16 [16][1024][512] (dead after GEMM1) / fusedb@12M, obuf@20M after
//   29-61M  w2t bf16 [16][1024][1024](dead after GEMM2)
//   61M     wq / rows / counts
//   63-64M  fw1t bf16 [512][1024]
//   65-97M  h1bf bf16 [16384][1024]
//   99-131M gbuf fp32 (dead after topk) then h2b bf16 [16384][1024]

#define EPSN 1e-5f

typedef __attribute__((ext_vector_type(8))) short v8s;   // 8 bf16 (4 VGPRs)
typedef __attribute__((ext_vector_type(4))) float v4f;   // 4 fp32 acc

typedef const unsigned int __attribute__((address_space(1)))* gas_u32;
typedef unsigned int __attribute__((address_space(3)))* las_u32;

__device__ __forceinline__ void glds16(const void* g, const void* l) {
    __builtin_amdgcn_global_load_lds((gas_u32)(uintptr_t)g, (las_u32)(uintptr_t)l, 16, 0, 0);
}

__device__ __forceinline__ float gelu_f(float x) {
    return 0.5f * x * (1.0f + erff(x * 0.70710678118654752440f));
}
__device__ __forceinline__ unsigned short f2bf(float x) {
    unsigned int u = __float_as_uint(x);
    u += 0x7fffu + ((u >> 16) & 1u);
    return (unsigned short)(u >> 16);
}
__device__ __forceinline__ float bf2f(unsigned short u) {
    return __uint_as_float(((unsigned int)u) << 16);
}

__global__ __launch_bounds__(256) void concat_kernel(const float4* __restrict__ wifi,
                                                     const float4* __restrict__ rfid,
                                                     float4* __restrict__ comb) {
    int gid = blockIdx.x * 256 + threadIdx.x;   // 4096 * 128
    int b = gid >> 7, c = gid & 127;
    comb[gid] = (c < 64) ? wifi[b * 64 + c] : rfid[b * 64 + (c - 64)];
}

__global__ __launch_bounds__(256) void cvt_f2b_kernel(const float4* __restrict__ in,
                                                      ushort4* __restrict__ out) {
    int gid = blockIdx.x * 256 + threadIdx.x;
    float4 v = in[gid];
    ushort4 o;
    o.x = f2bf(v.x); o.y = f2bf(v.y); o.z = f2bf(v.z); o.w = f2bf(v.w);
    out[gid] = o;
}

// in: per-expert [K][N] fp32 -> out: per-expert [N][K] bf16 (transpose+convert)
__global__ __launch_bounds__(256) void transpose_f2b(const float* __restrict__ in,
                                                     unsigned short* __restrict__ out,
                                                     int K, int N) {
    __shared__ float t[64][65];
    int e = blockIdx.z;
    int n0 = blockIdx.x << 6, k0 = blockIdx.y << 6;
    const float* ie = in + (long)e * K * N;
    unsigned short* oe = out + (long)e * N * K;
    int tid = threadIdx.x;
    int rr = tid >> 4, cc = (tid & 15) << 2;
#pragma unroll
    for (int p = 0; p < 4; ++p) {
        int k = (p << 4) + rr;
        float4 v = *(const float4*)(ie + (long)(k0 + k) * N + n0 + cc);
        t[k][cc + 0] = v.x; t[k][cc + 1] = v.y; t[k][cc + 2] = v.z; t[k][cc + 3] = v.w;
    }
    __syncthreads();
    int n = tid >> 2, kq = (tid & 3) << 4;
    unsigned short u[16];
#pragma unroll
    for (int j = 0; j < 16; ++j) u[j] = f2bf(t[kq + j][n]);
    uint4* dst = (uint4*)(oe + (long)(n0 + n) * K + k0 + kq);
    dst[0] = ((const uint4*)u)[0];
    dst[1] = ((const uint4*)u)[1];
}

// fp32 gate GEMM: 64x64 tile, BK=16, 256 threads, 4x4/thread. +bias only.
__global__ __launch_bounds__(256) void gate_gemm(
    const float* __restrict__ A, int lda,
    const float* __restrict__ W,
    const float* __restrict__ bias,
    float* __restrict__ out, int ldo, int N, int K)
{
    const int m0 = blockIdx.y << 6;
    const int n0 = blockIdx.x << 6;
    __shared__ float As[16][68];
    __shared__ float Bs[16][68];
    const int tid = threadIdx.x;
    const int ty = tid >> 4, tx = tid & 15;
    const int arow = tid >> 2;
    const int akq  = (tid & 3) << 2;
    const float* Aptr = A + (long)(m0 + arow) * lda + akq;
    const int bkr = tid >> 4;
    const int bnq = (tid & 15) << 2;
    const float* Bptr = W + (long)bkr * N + n0 + bnq;
    float acc[4][4] = {};
    for (int k0 = 0; k0 < K; k0 += 16) {
        float4 av = *(const float4*)(Aptr + k0);
        float4 bv = *(const float4*)(Bptr + (long)k0 * N);
        As[akq + 0][arow] = av.x;
        As[akq + 1][arow] = av.y;
        As[akq + 2][arow] = av.z;
        As[akq + 3][arow] = av.w;
        *(float4*)&Bs[bkr][bnq] = bv;
        __syncthreads();
#pragma unroll
        for (int kk = 0; kk < 16; ++kk) {
            float4 af = *(const float4*)&As[kk][ty << 2];
            float4 bf = *(const float4*)&Bs[kk][tx << 2];
            const float a4[4] = {af.x, af.y, af.z, af.w};
            const float b4[4] = {bf.x, bf.y, bf.z, bf.w};
#pragma unroll
            for (int i = 0; i < 4; ++i)
#pragma unroll
                for (int j = 0; j < 4; ++j)
                    acc[i][j] += a4[i] * b4[j];
        }
        __syncthreads();
    }
#pragma unroll
    for (int i = 0; i < 4; ++i) {
        int r = m0 + (ty << 2) + i;
        int c0 = n0 + (tx << 2);
        float4 v;
        v.x = acc[i][0] + bias[c0 + 0];
        v.y = acc[i][1] + bias[c0 + 1];
        v.z = acc[i][2] + bias[c0 + 2];
        v.w = acc[i][3] + bias[c0 + 3];
        *(float4*)(out + (long)r * ldo + c0) = v;
    }
}

// bf16 MFMA GEMM: 128x128 tile, BK=32, 256 threads (4 waves 2x2), 4x4 frags/wave.
// A [rows][K] bf16 row-major; Wt per-expert [N][K] bf16 (transposed).
// Epilogue: +bias, BN(eval), GELU; out bf16 or fp32.
// GATHER: A row = rows[e*4096+i] >> ASHIFT; out row = rows[e*4096+i].
template<int ASHIFT, bool GATHER, bool OUTBF>
__global__ __launch_bounds__(256) void mfma_gemm(
    const unsigned short* __restrict__ A, int K,
    const unsigned short* __restrict__ Wt, long wstride,
    const float* __restrict__ bias,
    const float* __restrict__ bng, const float* __restrict__ bnb,
    const float* __restrict__ bnm, const float* __restrict__ bnv,
    int pstride,
    void* __restrict__ outv, int ldo,
    const int* __restrict__ rows_, const int* __restrict__ counts, int M)
{
    const int e  = blockIdx.z;
    const int m0 = blockIdx.y << 7;
    const int n0 = blockIdx.x << 7;
    const int cnt = GATHER ? counts[e] : M;
    if (m0 >= cnt) return;

    __shared__ unsigned short Als[128 * 32];  // [row][k] 64B rows
    __shared__ unsigned short Bls[128 * 32];  // [n][k]
    __shared__ int rid[128];
    __shared__ int ain[128];

    const int tid = threadIdx.x;
    if (tid < 128) {
        int i = m0 + tid;
        int pk, ai;
        if (GATHER) {
            if (i < cnt) { pk = rows_[(e << 12) + i]; ai = pk >> ASHIFT; }
            else { pk = -1; ai = 0; }
        } else { pk = i; ai = i; }
        rid[tid] = pk;
        ain[tid] = ai;
    }
    __syncthreads();

    const int wave = tid >> 6, lane = tid & 63;
    const int wm = (wave >> 1) << 6, wn = (wave & 1) << 6;
    const int lrow = lane & 15, kch = lane >> 4;

    const int r0 = ain[tid >> 2];
    const int r1 = ain[64 + (tid >> 2)];
    const unsigned short* ap0 = A + (long)r0 * K + ((tid & 3) << 3);
    const unsigned short* ap1 = A + (long)r1 * K + ((tid & 3) << 3);
    const unsigned short* Wte = Wt + (long)e * wstride;
    const unsigned short* bp0 = Wte + (long)(n0 + (tid >> 2)) * K + ((tid & 3) << 3);
    const unsigned short* bp1 = Wte + (long)(n0 + 64 + (tid >> 2)) * K + ((tid & 3) << 3);

    v4f acc[4][4] = {};

    const int nk = K >> 5;
    for (int it = 0; it < nk; ++it) {
        glds16(ap0, Als + (wave << 9));
        glds16(ap1, Als + 2048 + (wave << 9));
        glds16(bp0, Bls + (wave << 9));
        glds16(bp1, Bls + 2048 + (wave << 9));
        ap0 += 32; ap1 += 32; bp0 += 32; bp1 += 32;
        __syncthreads();

        v8s av[4], bv[4];
#pragma unroll
        for (int f = 0; f < 4; ++f) {
            av[f] = *(const v8s*)(Als + ((wm + (f << 4) + lrow) << 5) + (kch << 3));
            bv[f] = *(const v8s*)(Bls + ((wn + (f << 4) + lrow) << 5) + (kch << 3));
        }
#pragma unroll
        for (int fi = 0; fi < 4; ++fi)
#pragma unroll
            for (int fj = 0; fj < 4; ++fj)
                acc[fi][fj] = __builtin_amdgcn_mfma_f32_16x16x32_bf16(
                    av[fi], bv[fj], acc[fi][fj], 0, 0, 0);
        __syncthreads();
    }

    // epilogue: C/D layout col=lane&15, row=(lane>>4)*4+reg
#pragma unroll
    for (int fj = 0; fj < 4; ++fj) {
        const int c = n0 + wn + (fj << 4) + lrow;
        const int pc = e * pstride + c;
        const float bs = bias[pc];
        const float sc = bng[pc] * rsqrtf(bnv[pc] + EPSN);
        const float mn = bnm[pc], bb = bnb[pc];
#pragma unroll
        for (int fi = 0; fi < 4; ++fi) {
#pragma unroll
            for (int r = 0; r < 4; ++r) {
                const int lr = wm + (fi << 4) + (kch << 2) + r;
                const int orow = rid[lr];
                if (orow < 0) continue;
                float x = acc[fi][fj][r] + bs;
                x = (x - mn) * sc + bb;
                x = gelu_f(x);
                if (OUTBF)
                    ((unsigned short*)outv)[(long)orow * ldo + c] = f2bf(x);
                else
                    ((float*)outv)[(long)orow * ldo + c] = x;
            }
        }
    }
}

__global__ __launch_bounds__(256) void ln_gelu_kernel(float* __restrict__ g,
                                                      const float* __restrict__ lng,
                                                      const float* __restrict__ lnb) {
    int b = blockIdx.x;
    int tid = threadIdx.x;
    int c = tid << 2;
    float4 v = *(const float4*)(g + (long)b * 1024 + c);
    float s = v.x + v.y + v.z + v.w;
    float q = v.x * v.x + v.y * v.y + v.z * v.z + v.w * v.w;
    for (int off = 32; off > 0; off >>= 1) {
        s += __shfl_down(s, off);
        q += __shfl_down(q, off);
    }
    __shared__ float rs[4], rq[4];
    int wid = tid >> 6;
    if ((tid & 63) == 0) { rs[wid] = s; rq[wid] = q; }
    __syncthreads();
    float S = rs[0] + rs[1] + rs[2] + rs[3];
    float Q = rq[0] + rq[1] + rq[2] + rq[3];
    float mu = S * (1.0f / 1024.0f);
    float var = Q * (1.0f / 1024.0f) - mu * mu;
    float rstd = rsqrtf(var + EPSN);
    float4 o;
    o.x = gelu_f((v.x - mu) * rstd * lng[c + 0] + lnb[c + 0]);
    o.y = gelu_f((v.y - mu) * rstd * lng[c + 1] + lnb[c + 1]);
    o.z = gelu_f((v.z - mu) * rstd * lng[c + 2] + lnb[c + 2]);
    o.w = gelu_f((v.w - mu) * rstd * lng[c + 3] + lnb[c + 3]);
    *(float4*)(g + (long)b * 1024 + c) = o;
}

__global__ __launch_bounds__(256) void gate_topk_kernel(
    const float* __restrict__ g, const float* __restrict__ w2, const float* __restrict__ b2,
    float* __restrict__ wout, int* __restrict__ rows, int* __restrict__ counts)
{
    int b = blockIdx.x;
    int tid = threadIdx.x;
    int e = tid & 15, chunk = tid >> 4;
    const float* gr = g + (long)b * 1024;
    float p = 0.f;
    for (int i = 0; i < 64; ++i) {
        int idx = chunk * 64 + i;
        p += gr[idx] * w2[idx * 16 + e];
    }
    __shared__ float red[16][17];
    red[chunk][e] = p;
    __syncthreads();
    __shared__ float logit[16];
    if (tid < 16) {
        float s = b2[tid];
        for (int c = 0; c < 16; ++c) s += red[c][tid];
        logit[tid] = s;
    }
    __syncthreads();
    if (tid == 0) {
        float m = logit[0];
        for (int i = 1; i < 16; ++i) m = fmaxf(m, logit[i]);
        float p16[16]; float Z = 0.f;
        for (int i = 0; i < 16; ++i) { p16[i] = expf(logit[i] - m); }
        for (int i = 0; i < 16; ++i) Z += p16[i];
        float inv = 1.0f / Z;
        for (int i = 0; i < 16; ++i) p16[i] *= inv;
        int idx4[4]; float v4[4];
        bool used[16] = {};
        for (int k = 0; k < 4; ++k) {
            int bi = 0; float bvv = -1.f;
            for (int i = 0; i < 16; ++i)
                if (!used[i] && p16[i] > bvv) { bvv = p16[i]; bi = i; }
            used[bi] = true; idx4[k] = bi; v4[k] = bvv;
        }
        float q[4]; float Z2 = 0.f;
        for (int k = 0; k < 4; ++k) { q[k] = expf(v4[k] - v4[0]); Z2 += q[k]; }
        float inv2 = 1.0f / Z2;
        for (int k = 0; k < 4; ++k) {
            wout[b * 4 + k] = q[k] * inv2;
            int ee = idx4[k];
            int j = atomicAdd(&counts[ee], 1);
            rows[ee * 4096 + j] = (b << 2) | k;
        }
    }
}

// weighted top-4 combine, bf16 in -> bf16 out
__global__ __launch_bounds__(256) void combine_bf_kernel(const ushort4* __restrict__ h2b,
                                                         const float* __restrict__ w,
                                                         ushort4* __restrict__ fusedb) {
    int gid = blockIdx.x * 256 + threadIdx.x;  // 4096*256
    int b = gid >> 8, c = gid & 255;
    float a0 = 0.f, a1 = 0.f, a2 = 0.f, a3 = 0.f;
#pragma unroll
    for (int k = 0; k < 4; ++k) {
        float wk = w[b * 4 + k];
        ushort4 v = h2b[(long)(b * 4 + k) * 256 + c];
        a0 += wk * bf2f(v.x); a1 += wk * bf2f(v.y);
        a2 += wk * bf2f(v.z); a3 += wk * bf2f(v.w);
    }
    ushort4 o;
    o.x = f2bf(a0); o.y = f2bf(a1); o.z = f2bf(a2); o.w = f2bf(a3);
    fusedb[gid] = o;
}

__global__ __launch_bounds__(256) void fin2_kernel(const float* __restrict__ o,
                                                   const float* __restrict__ w2,
                                                   const float* __restrict__ b2,
                                                   float* __restrict__ out) {
    __shared__ float ws[512 * 20];
    int tid = threadIdx.x;
    for (int i = tid; i < 512 * 20; i += 256) ws[i] = w2[i];
    __syncthreads();
    int r = blockIdx.x * 64 + (tid >> 2);
    int c0 = (tid & 3) * 5;
    float acc[5];
#pragma unroll
    for (int j = 0; j < 5; ++j) acc[j] = b2[c0 + j];
    const float* orow = o + (long)r * 512;
    for (int i = 0; i < 512; ++i) {
        float v = orow[i];
#pragma unroll
        for (int j = 0; j < 5; ++j) acc[j] += v * ws[i * 20 + c0 + j];
    }
#pragma unroll
    for (int j = 0; j < 5; ++j) out[r * 20 + c0 + j] = acc[j];
}

extern "C" void kernel_launch(void* const* d_in, const int* in_sizes, int n_in,
                              void* d_out, int out_size, void* d_ws, size_t ws_size,
                              hipStream_t stream) {
    const float* wifi    = (const float*)d_in[0];
    const float* rfid    = (const float*)d_in[1];
    const float* gate_w1 = (const float*)d_in[2];
    const float* gate_b1 = (const float*)d_in[3];
    const float* gln_g   = (const float*)d_in[4];
    const float* gln_b   = (const float*)d_in[5];
    const float* gate_w2 = (const float*)d_in[6];
    const float* gate_b2 = (const float*)d_in[7];
    const float* exp_w1  = (const float*)d_in[8];
    const float* exp_b1  = (const float*)d_in[9];
    const float* bn1g    = (const float*)d_in[10];
    const float* bn1b    = (const float*)d_in[11];
    const float* bn1m    = (const float*)d_in[12];
    const float* bn1v    = (const float*)d_in[13];
    const float* exp_w2  = (const float*)d_in[14];
    const float* exp_b2  = (const float*)d_in[15];
    const float* bn2g    = (const float*)d_in[16];
    const float* bn2b    = (const float*)d_in[17];
    const float* bn2m    = (const float*)d_in[18];
    const float* bn2v    = (const float*)d_in[19];
    const float* fin_w1  = (const float*)d_in[20];
    const float* fin_b1  = (const float*)d_in[21];
    const float* fbng    = (const float*)d_in[22];
    const float* fbnb    = (const float*)d_in[23];
    const float* fbnm    = (const float*)d_in[24];
    const float* fbnv    = (const float*)d_in[25];
    const float* fin_w2  = (const float*)d_in[26];
    const float* fin_b2  = (const float*)d_in[27];
    float* out = (float*)d_out;

    const size_t MBy = 1u << 20;
    char* W = (char*)d_ws;
    float*          combined = (float*)         (W + 0);
    unsigned short* cbf      = (unsigned short*)(W + 8 * MBy);
    unsigned short* w1t      = (unsigned short*)(W + 12 * MBy);
    unsigned short* fusedb   = (unsigned short*)(W + 12 * MBy);   // after w1t dead
    float*          obuf     = (float*)         (W + 20 * MBy);   // after w1t dead
    unsigned short* w2t      = (unsigned short*)(W + 29 * MBy);
    float*          wq       = (float*)         (W + 61 * MBy);
    int*            rows     = (int*)           (W + 61 * MBy + (1 << 16));
    int*            counts   = (int*)           (W + 61 * MBy + (1 << 16) + (1 << 18));
    unsigned short* fw1t     = (unsigned short*)(W + 63 * MBy);
    unsigned short* h1bf     = (unsigned short*)(W + 65 * MBy);
    float*          gbuf     = (float*)         (W + 99 * MBy);
    unsigned short* h2b      = (unsigned short*)(W + 99 * MBy);   // after gbuf dead

    hipMemsetAsync(counts, 0, 16 * sizeof(int), stream);

    concat_kernel<<<2048, 256, 0, stream>>>((const float4*)wifi, (const float4*)rfid,
                                            (float4*)combined);
    cvt_f2b_kernel<<<2048, 256, 0, stream>>>((const float4*)combined, (ushort4*)cbf);

    // weight transposes fp32 [K][N] -> bf16 [N][K]
    transpose_f2b<<<dim3(16, 8, 16), 256, 0, stream>>>(exp_w1, w1t, 512, 1024);
    transpose_f2b<<<dim3(16, 16, 16), 256, 0, stream>>>(exp_w2, w2t, 1024, 1024);
    transpose_f2b<<<dim3(8, 16, 1), 256, 0, stream>>>(fin_w1, fw1t, 1024, 512);

    // gate (fp32): GEMM1 -> LN+GELU -> logits/softmax/top4
    gate_gemm<<<dim3(16, 64, 1), 256, 0, stream>>>(combined, 512, gate_w1, gate_b1,
                                                   gbuf, 1024, 1024, 512);
    ln_gelu_kernel<<<4096, 256, 0, stream>>>(gbuf, gln_g, gln_b);
    gate_topk_kernel<<<4096, 256, 0, stream>>>(gbuf, gate_w2, gate_b2, wq, rows, counts);

    // expert GEMM1 (gathered, bf16 MFMA): cbf rows -> h1bf[slot]
    mfma_gemm<2, true, true><<<dim3(8, 32, 16), 256, 0, stream>>>(
        cbf, 512, w1t, (long)512 * 1024, exp_b1,
        bn1g, bn1b, bn1m, bn1v, 1024,
        h1bf, 1024, rows, counts, 4096);

    // expert GEMM2 (gathered, bf16 MFMA): h1bf[slot] -> h2b[slot]
    mfma_gemm<0, true, true><<<dim3(8, 32, 16), 256, 0, stream>>>(
        h1bf, 1024, w2t, (long)1024 * 1024, exp_b2,
        bn2g, bn2b, bn2m, bn2v, 1024,
        h2b, 1024, rows, counts, 4096);

    combine_bf_kernel<<<4096, 256, 0, stream>>>((const ushort4*)h2b, wq, (ushort4*)fusedb);

    // final GEMM1 (bf16 MFMA): fusedb -> obuf fp32, BN+GELU
    mfma_gemm<0, false, false><<<dim3(4, 32, 1), 256, 0, stream>>>(
        fusedb, 1024, fw1t, 0, fin_b1,
        fbng, fbnb, fbnm, fbnv, 0,
        obuf, 512, nullptr, nullptr, 4096);

    fin2_kernel<<<64, 256, 0, stream>>>(obuf, fin_w2, fin_b2, out);
}

// Round 3
// 557.713 us; speedup vs baseline: 2.3740x; 1.2564x over previous
//
#include <hip/hip_runtime.h>

// MoE_77644418777543 — round 2: kill the 200µs serial gate_topk tail.
// Fused ln_topk kernel: LN+GELU -> LDS -> chunk-parallel dots -> wave-parallel
// softmax/top4 via shfl_xor butterflies (no scratch arrays, no serial expf).
// Expert GEMMs / fin1 unchanged (bf16 MFMA, 128x128x32, global_load_lds 16B).
//
// Workspace (bytes, MB = 2^20), aliased by liveness:
//   0-8M    combined fp32            (gate gemm; then dead)
//   8-12M   cbf bf16                 (dead after expert GEMM1)
//   12-28M  w1t bf16 [16][1024][512] (dead after GEMM1) / fusedb@12M, obuf@20M after
//   29-61M  w2t bf16 [16][1024][1024](dead after GEMM2)
//   61M     wq / rows / counts
//   63-64M  fw1t bf16 [512][1024]
//   65-97M  h1bf bf16 [16384][1024]
//   99-131M gbuf fp32 (dead after ln_topk) then h2b bf16 [16384][1024]

#define EPSN 1e-5f

typedef __attribute__((ext_vector_type(8))) short v8s;   // 8 bf16 (4 VGPRs)
typedef __attribute__((ext_vector_type(4))) float v4f;   // 4 fp32 acc

typedef const unsigned int __attribute__((address_space(1)))* gas_u32;
typedef unsigned int __attribute__((address_space(3)))* las_u32;

__device__ __forceinline__ void glds16(const void* g, const void* l) {
    __builtin_amdgcn_global_load_lds((gas_u32)(uintptr_t)g, (las_u32)(uintptr_t)l, 16, 0, 0);
}

__device__ __forceinline__ float gelu_f(float x) {
    return 0.5f * x * (1.0f + erff(x * 0.70710678118654752440f));
}
__device__ __forceinline__ unsigned short f2bf(float x) {
    unsigned int u = __float_as_uint(x);
    u += 0x7fffu + ((u >> 16) & 1u);
    return (unsigned short)(u >> 16);
}
__device__ __forceinline__ float bf2f(unsigned short u) {
    return __uint_as_float(((unsigned int)u) << 16);
}

// concat wifi|rfid -> combined fp32, and also emit bf16 copy for MFMA path
__global__ __launch_bounds__(256) void concat_kernel(const float4* __restrict__ wifi,
                                                     const float4* __restrict__ rfid,
                                                     float4* __restrict__ comb,
                                                     ushort4* __restrict__ cbf) {
    int gid = blockIdx.x * 256 + threadIdx.x;   // 4096 * 128
    int b = gid >> 7, c = gid & 127;
    float4 v = (c < 64) ? wifi[b * 64 + c] : rfid[b * 64 + (c - 64)];
    comb[gid] = v;
    ushort4 o;
    o.x = f2bf(v.x); o.y = f2bf(v.y); o.z = f2bf(v.z); o.w = f2bf(v.w);
    cbf[gid] = o;
}

// in: per-expert [K][N] fp32 -> out: per-expert [N][K] bf16 (transpose+convert)
__global__ __launch_bounds__(256) void transpose_f2b(const float* __restrict__ in,
                                                     unsigned short* __restrict__ out,
                                                     int K, int N) {
    __shared__ float t[64][65];
    int e = blockIdx.z;
    int n0 = blockIdx.x << 6, k0 = blockIdx.y << 6;
    const float* ie = in + (long)e * K * N;
    unsigned short* oe = out + (long)e * N * K;
    int tid = threadIdx.x;
    int rr = tid >> 4, cc = (tid & 15) << 2;
#pragma unroll
    for (int p = 0; p < 4; ++p) {
        int k = (p << 4) + rr;
        float4 v = *(const float4*)(ie + (long)(k0 + k) * N + n0 + cc);
        t[k][cc + 0] = v.x; t[k][cc + 1] = v.y; t[k][cc + 2] = v.z; t[k][cc + 3] = v.w;
    }
    __syncthreads();
    int n = tid >> 2, kq = (tid & 3) << 4;
    unsigned short u[16];
#pragma unroll
    for (int j = 0; j < 16; ++j) u[j] = f2bf(t[kq + j][n]);
    uint4* dst = (uint4*)(oe + (long)(n0 + n) * K + k0 + kq);
    dst[0] = ((const uint4*)u)[0];
    dst[1] = ((const uint4*)u)[1];
}

// fp32 gate GEMM: 64x64 tile, BK=16, 256 threads, 4x4/thread. +bias only.
__global__ __launch_bounds__(256) void gate_gemm(
    const float* __restrict__ A, int lda,
    const float* __restrict__ W,
    const float* __restrict__ bias,
    float* __restrict__ out, int ldo, int N, int K)
{
    const int m0 = blockIdx.y << 6;
    const int n0 = blockIdx.x << 6;
    __shared__ float As[16][68];
    __shared__ float Bs[16][68];
    const int tid = threadIdx.x;
    const int ty = tid >> 4, tx = tid & 15;
    const int arow = tid >> 2;
    const int akq  = (tid & 3) << 2;
    const float* Aptr = A + (long)(m0 + arow) * lda + akq;
    const int bkr = tid >> 4;
    const int bnq = (tid & 15) << 2;
    const float* Bptr = W + (long)bkr * N + n0 + bnq;
    float acc[4][4] = {};
    for (int k0 = 0; k0 < K; k0 += 16) {
        float4 av = *(const float4*)(Aptr + k0);
        float4 bv = *(const float4*)(Bptr + (long)k0 * N);
        As[akq + 0][arow] = av.x;
        As[akq + 1][arow] = av.y;
        As[akq + 2][arow] = av.z;
        As[akq + 3][arow] = av.w;
        *(float4*)&Bs[bkr][bnq] = bv;
        __syncthreads();
#pragma unroll
        for (int kk = 0; kk < 16; ++kk) {
            float4 af = *(const float4*)&As[kk][ty << 2];
            float4 bf = *(const float4*)&Bs[kk][tx << 2];
            const float a4[4] = {af.x, af.y, af.z, af.w};
            const float b4[4] = {bf.x, bf.y, bf.z, bf.w};
#pragma unroll
            for (int i = 0; i < 4; ++i)
#pragma unroll
                for (int j = 0; j < 4; ++j)
                    acc[i][j] += a4[i] * b4[j];
        }
        __syncthreads();
    }
#pragma unroll
    for (int i = 0; i < 4; ++i) {
        int r = m0 + (ty << 2) + i;
        int c0 = n0 + (tx << 2);
        float4 v;
        v.x = acc[i][0] + bias[c0 + 0];
        v.y = acc[i][1] + bias[c0 + 1];
        v.z = acc[i][2] + bias[c0 + 2];
        v.w = acc[i][3] + bias[c0 + 3];
        *(float4*)(out + (long)r * ldo + c0) = v;
    }
}

// Fused: LayerNorm+GELU (row of 1024) -> gate logits (16) -> softmax -> top4
// -> renorm softmax -> scatter (rows/counts/weights). One block per row.
// Tail is wave-parallel on lanes 0..15 via shfl_xor: no scratch arrays.
__global__ __launch_bounds__(256) void ln_topk_kernel(
    const float* __restrict__ g,
    const float* __restrict__ lng, const float* __restrict__ lnb,
    const float* __restrict__ w2, const float* __restrict__ b2,
    float* __restrict__ wout, int* __restrict__ rows_, int* __restrict__ counts)
{
    __shared__ float gs[1024];
    __shared__ float red[16][17];
    __shared__ float rs[4], rq[4];
    const int b = blockIdx.x;
    const int tid = threadIdx.x;
    const int c = tid << 2;

    float4 v = *(const float4*)(g + (long)b * 1024 + c);
    float s = v.x + v.y + v.z + v.w;
    float q = v.x * v.x + v.y * v.y + v.z * v.z + v.w * v.w;
    for (int off = 32; off > 0; off >>= 1) {
        s += __shfl_down(s, off);
        q += __shfl_down(q, off);
    }
    int wid = tid >> 6;
    if ((tid & 63) == 0) { rs[wid] = s; rq[wid] = q; }
    __syncthreads();
    float S = rs[0] + rs[1] + rs[2] + rs[3];
    float Q = rq[0] + rq[1] + rq[2] + rq[3];
    float mu = S * (1.0f / 1024.0f);
    float var = Q * (1.0f / 1024.0f) - mu * mu;
    float rstd = rsqrtf(var + EPSN);
    gs[c + 0] = gelu_f((v.x - mu) * rstd * lng[c + 0] + lnb[c + 0]);
    gs[c + 1] = gelu_f((v.y - mu) * rstd * lng[c + 1] + lnb[c + 1]);
    gs[c + 2] = gelu_f((v.z - mu) * rstd * lng[c + 2] + lnb[c + 2]);
    gs[c + 3] = gelu_f((v.w - mu) * rstd * lng[c + 3] + lnb[c + 3]);
    __syncthreads();

    // dots: thread (chunk=tid>>4, e=tid&15); gs broadcast, w2 coalesced
    const int e = tid & 15, chunk = tid >> 4;
    float p = 0.f;
#pragma unroll 8
    for (int i = 0; i < 64; ++i) {
        int idx = (chunk << 6) + i;
        p = fmaf(gs[idx], w2[(idx << 4) + e], p);
    }
    red[chunk][e] = p;
    __syncthreads();

    if (tid < 64) {
        float logit = -1e30f;
        if (tid < 16) {
            logit = b2[tid];
#pragma unroll
            for (int cc = 0; cc < 16; ++cc) logit += red[cc][tid];
        }
        // softmax over lanes 0..15 (xor masks <16 keep the group closed)
        float m = logit;
#pragma unroll
        for (int mk = 8; mk >= 1; mk >>= 1) m = fmaxf(m, __shfl_xor(m, mk));
        float pe = (tid < 16) ? expf(logit - m) : 0.f;
        float Z = pe;
#pragma unroll
        for (int mk = 8; mk >= 1; mk >>= 1) Z += __shfl_xor(Z, mk);
        float prob = pe / Z;

        // top-4 by repeated shuffle-argmax, lowest-index tiebreak (lax.top_k order)
        float cur = (tid < 16) ? prob : -1.f;
        const int myi = tid & 15;
        float tv0, tv1, tv2, tv3;
        int ti0, ti1, ti2, ti3;
#define ARGMAX16(TV, TI)                                                     \
        {   float vv = cur; int ii = myi;                                    \
            _Pragma("unroll")                                                \
            for (int mk = 8; mk >= 1; mk >>= 1) {                            \
                float ov = __shfl_xor(vv, mk); int oi = __shfl_xor(ii, mk);  \
                if (ov > vv || (ov == vv && oi < ii)) { vv = ov; ii = oi; }  \
            }                                                                \
            TV = vv; TI = ii;                                                \
            if (myi == ii) cur = -1.f;                                       \
        }
        ARGMAX16(tv0, ti0)
        ARGMAX16(tv1, ti1)
        ARGMAX16(tv2, ti2)
        ARGMAX16(tv3, ti3)
#undef ARGMAX16

        // renormalized softmax over the 4 (uniform registers in lanes 0..15)
        float q0 = 1.f;                    // expf(tv0 - tv0)
        float q1 = expf(tv1 - tv0);
        float q2 = expf(tv2 - tv0);
        float q3 = expf(tv3 - tv0);
        float iZ2 = 1.f / (q0 + q1 + q2 + q3);
        if (tid < 4) {
            float wk = (tid == 0) ? q0 : (tid == 1) ? q1 : (tid == 2) ? q2 : q3;
            int   ee = (tid == 0) ? ti0 : (tid == 1) ? ti1 : (tid == 2) ? ti2 : ti3;
            wout[(b << 2) + tid] = wk * iZ2;
            int j = atomicAdd(&counts[ee], 1);
            rows_[(ee << 12) + j] = (b << 2) | tid;
        }
    }
}

// bf16 MFMA GEMM: 128x128 tile, BK=32, 256 threads (4 waves 2x2), 4x4 frags/wave.
template<int ASHIFT, bool GATHER, bool OUTBF>
__global__ __launch_bounds__(256) void mfma_gemm(
    const unsigned short* __restrict__ A, int K,
    const unsigned short* __restrict__ Wt, long wstride,
    const float* __restrict__ bias,
    const float* __restrict__ bng, const float* __restrict__ bnb,
    const float* __restrict__ bnm, const float* __restrict__ bnv,
    int pstride,
    void* __restrict__ outv, int ldo,
    const int* __restrict__ rows_, const int* __restrict__ counts, int M)
{
    const int e  = blockIdx.z;
    const int m0 = blockIdx.y << 7;
    const int n0 = blockIdx.x << 7;
    const int cnt = GATHER ? counts[e] : M;
    if (m0 >= cnt) return;

    __shared__ unsigned short Als[128 * 32];  // [row][k] 64B rows
    __shared__ unsigned short Bls[128 * 32];  // [n][k]
    __shared__ int rid[128];
    __shared__ int ain[128];

    const int tid = threadIdx.x;
    if (tid < 128) {
        int i = m0 + tid;
        int pk, ai;
        if (GATHER) {
            if (i < cnt) { pk = rows_[(e << 12) + i]; ai = pk >> ASHIFT; }
            else { pk = -1; ai = 0; }
        } else { pk = i; ai = i; }
        rid[tid] = pk;
        ain[tid] = ai;
    }
    __syncthreads();

    const int wave = tid >> 6, lane = tid & 63;
    const int wm = (wave >> 1) << 6, wn = (wave & 1) << 6;
    const int lrow = lane & 15, kch = lane >> 4;

    const int r0 = ain[tid >> 2];
    const int r1 = ain[64 + (tid >> 2)];
    const unsigned short* ap0 = A + (long)r0 * K + ((tid & 3) << 3);
    const unsigned short* ap1 = A + (long)r1 * K + ((tid & 3) << 3);
    const unsigned short* Wte = Wt + (long)e * wstride;
    const unsigned short* bp0 = Wte + (long)(n0 + (tid >> 2)) * K + ((tid & 3) << 3);
    const unsigned short* bp1 = Wte + (long)(n0 + 64 + (tid >> 2)) * K + ((tid & 3) << 3);

    v4f acc[4][4] = {};

    const int nk = K >> 5;
    for (int it = 0; it < nk; ++it) {
        glds16(ap0, Als + (wave << 9));
        glds16(ap1, Als + 2048 + (wave << 9));
        glds16(bp0, Bls + (wave << 9));
        glds16(bp1, Bls + 2048 + (wave << 9));
        ap0 += 32; ap1 += 32; bp0 += 32; bp1 += 32;
        __syncthreads();

        v8s av[4], bv[4];
#pragma unroll
        for (int f = 0; f < 4; ++f) {
            av[f] = *(const v8s*)(Als + ((wm + (f << 4) + lrow) << 5) + (kch << 3));
            bv[f] = *(const v8s*)(Bls + ((wn + (f << 4) + lrow) << 5) + (kch << 3));
        }
#pragma unroll
        for (int fi = 0; fi < 4; ++fi)
#pragma unroll
            for (int fj = 0; fj < 4; ++fj)
                acc[fi][fj] = __builtin_amdgcn_mfma_f32_16x16x32_bf16(
                    av[fi], bv[fj], acc[fi][fj], 0, 0, 0);
        __syncthreads();
    }

    // epilogue: C/D layout col=lane&15, row=(lane>>4)*4+reg
#pragma unroll
    for (int fj = 0; fj < 4; ++fj) {
        const int c = n0 + wn + (fj << 4) + lrow;
        const int pc = e * pstride + c;
        const float bs = bias[pc];
        const float sc = bng[pc] * rsqrtf(bnv[pc] + EPSN);
        const float mn = bnm[pc], bb = bnb[pc];
#pragma unroll
        for (int fi = 0; fi < 4; ++fi) {
#pragma unroll
            for (int r = 0; r < 4; ++r) {
                const int lr = wm + (fi << 4) + (kch << 2) + r;
                const int orow = rid[lr];
                if (orow < 0) continue;
                float x = acc[fi][fj][r] + bs;
                x = (x - mn) * sc + bb;
                x = gelu_f(x);
                if (OUTBF)
                    ((unsigned short*)outv)[(long)orow * ldo + c] = f2bf(x);
                else
                    ((float*)outv)[(long)orow * ldo + c] = x;
            }
        }
    }
}

// weighted top-4 combine, bf16 in -> bf16 out
__global__ __launch_bounds__(256) void combine_bf_kernel(const ushort4* __restrict__ h2b,
                                                         const float* __restrict__ w,
                                                         ushort4* __restrict__ fusedb) {
    int gid = blockIdx.x * 256 + threadIdx.x;  // 4096*256
    int b = gid >> 8, c = gid & 255;
    float a0 = 0.f, a1 = 0.f, a2 = 0.f, a3 = 0.f;
#pragma unroll
    for (int k = 0; k < 4; ++k) {
        float wk = w[b * 4 + k];
        ushort4 v = h2b[(long)(b * 4 + k) * 256 + c];
        a0 += wk * bf2f(v.x); a1 += wk * bf2f(v.y);
        a2 += wk * bf2f(v.z); a3 += wk * bf2f(v.w);
    }
    ushort4 o;
    o.x = f2bf(a0); o.y = f2bf(a1); o.z = f2bf(a2); o.w = f2bf(a3);
    fusedb[gid] = o;
}

__global__ __launch_bounds__(256) void fin2_kernel(const float* __restrict__ o,
                                                   const float* __restrict__ w2,
                                                   const float* __restrict__ b2,
                                                   float* __restrict__ out) {
    __shared__ float ws[512 * 20];
    int tid = threadIdx.x;
    for (int i = tid; i < 512 * 20; i += 256) ws[i] = w2[i];
    __syncthreads();
    int r = blockIdx.x * 64 + (tid >> 2);
    int c0 = (tid & 3) * 5;
    float acc[5];
#pragma unroll
    for (int j = 0; j < 5; ++j) acc[j] = b2[c0 + j];
    const float* orow = o + (long)r * 512;
    for (int i = 0; i < 512; ++i) {
        float v = orow[i];
#pragma unroll
        for (int j = 0; j < 5; ++j) acc[j] += v * ws[i * 20 + c0 + j];
    }
#pragma unroll
    for (int j = 0; j < 5; ++j) out[r * 20 + c0 + j] = acc[j];
}

extern "C" void kernel_launch(void* const* d_in, const int* in_sizes, int n_in,
                              void* d_out, int out_size, void* d_ws, size_t ws_size,
                              hipStream_t stream) {
    const float* wifi    = (const float*)d_in[0];
    const float* rfid    = (const float*)d_in[1];
    const float* gate_w1 = (const float*)d_in[2];
    const float* gate_b1 = (const float*)d_in[3];
    const float* gln_g   = (const float*)d_in[4];
    const float* gln_b   = (const float*)d_in[5];
    const float* gate_w2 = (const float*)d_in[6];
    const float* gate_b2 = (const float*)d_in[7];
    const float* exp_w1  = (const float*)d_in[8];
    const float* exp_b1  = (const float*)d_in[9];
    const float* bn1g    = (const float*)d_in[10];
    const float* bn1b    = (const float*)d_in[11];
    const float* bn1m    = (const float*)d_in[12];
    const float* bn1v    = (const float*)d_in[13];
    const float* exp_w2  = (const float*)d_in[14];
    const float* exp_b2  = (const float*)d_in[15];
    const float* bn2g    = (const float*)d_in[16];
    const float* bn2b    = (const float*)d_in[17];
    const float* bn2m    = (const float*)d_in[18];
    const float* bn2v    = (const float*)d_in[19];
    const float* fin_w1  = (const float*)d_in[20];
    const float* fin_b1  = (const float*)d_in[21];
    const float* fbng    = (const float*)d_in[22];
    const float* fbnb    = (const float*)d_in[23];
    const float* fbnm    = (const float*)d_in[24];
    const float* fbnv    = (const float*)d_in[25];
    const float* fin_w2  = (const float*)d_in[26];
    const float* fin_b2  = (const float*)d_in[27];
    float* out = (float*)d_out;

    const size_t MBy = 1u << 20;
    char* W = (char*)d_ws;
    float*          combined = (float*)         (W + 0);
    unsigned short* cbf      = (unsigned short*)(W + 8 * MBy);
    unsigned short* w1t      = (unsigned short*)(W + 12 * MBy);
    unsigned short* fusedb   = (unsigned short*)(W + 12 * MBy);   // after w1t dead
    float*          obuf     = (float*)         (W + 20 * MBy);   // after w1t dead
    unsigned short* w2t      = (unsigned short*)(W + 29 * MBy);
    float*          wq       = (float*)         (W + 61 * MBy);
    int*            rows     = (int*)           (W + 61 * MBy + (1 << 16));
    int*            counts   = (int*)           (W + 61 * MBy + (1 << 16) + (1 << 18));
    unsigned short* fw1t     = (unsigned short*)(W + 63 * MBy);
    unsigned short* h1bf     = (unsigned short*)(W + 65 * MBy);
    float*          gbuf     = (float*)         (W + 99 * MBy);
    unsigned short* h2b      = (unsigned short*)(W + 99 * MBy);   // after gbuf dead

    hipMemsetAsync(counts, 0, 16 * sizeof(int), stream);

    concat_kernel<<<2048, 256, 0, stream>>>((const float4*)wifi, (const float4*)rfid,
                                            (float4*)combined, (ushort4*)cbf);

    // weight transposes fp32 [K][N] -> bf16 [N][K]
    transpose_f2b<<<dim3(16, 8, 16), 256, 0, stream>>>(exp_w1, w1t, 512, 1024);
    transpose_f2b<<<dim3(16, 16, 16), 256, 0, stream>>>(exp_w2, w2t, 1024, 1024);
    transpose_f2b<<<dim3(8, 16, 1), 256, 0, stream>>>(fin_w1, fw1t, 1024, 512);

    // gate (fp32): GEMM1 -> fused LN/GELU/logits/softmax/top4
    gate_gemm<<<dim3(16, 64, 1), 256, 0, stream>>>(combined, 512, gate_w1, gate_b1,
                                                   gbuf, 1024, 1024, 512);
    ln_topk_kernel<<<4096, 256, 0, stream>>>(gbuf, gln_g, gln_b, gate_w2, gate_b2,
                                             wq, rows, counts);

    // expert GEMM1 (gathered, bf16 MFMA): cbf rows -> h1bf[slot]
    mfma_gemm<2, true, true><<<dim3(8, 32, 16), 256, 0, stream>>>(
        cbf, 512, w1t, (long)512 * 1024, exp_b1,
        bn1g, bn1b, bn1m, bn1v, 1024,
        h1bf, 1024, rows, counts, 4096);

    // expert GEMM2 (gathered, bf16 MFMA): h1bf[slot] -> h2b[slot]
    mfma_gemm<0, true, true><<<dim3(8, 32, 16), 256, 0, stream>>>(
        h1bf, 1024, w2t, (long)1024 * 1024, exp_b2,
        bn2g, bn2b, bn2m, bn2v, 1024,
        h2b, 1024, rows, counts, 4096);

    combine_bf_kernel<<<4096, 256, 0, stream>>>((const ushort4*)h2b, wq, (ushort4*)fusedb);

    // final GEMM1 (bf16 MFMA): fusedb -> obuf fp32, BN+GELU
    mfma_gemm<0, false, false><<<dim3(4, 32, 1), 256, 0, stream>>>(
        fusedb, 1024, fw1t, 0, fin_b1,
        fbng, fbnb, fbnm, fbnv, 0,
        obuf, 512, nullptr, nullptr, 4096);

    fin2_kernel<<<64, 256, 0, stream>>>(obuf, fin_w2, fin_b2, out);
}

// Round 4
// 544.772 us; speedup vs baseline: 2.4304x; 1.0238x over previous
//
#include <hip/hip_runtime.h>

// MoE_77644418777543 — round 3: fix gathered-GEMM CU load imbalance.
// Old grid (n, m, expert): working blocks were ids 256z+(0..63) -> all on CUs
// 0..63 (21% occupancy measured). New grid (n, expert, m): working ids 0..1023
// spread over all 256 CUs. Also: gate_gemm 128x64 tile (2x FMA/LDS-byte),
// fin1 uses TM=64 tile so its grid is 256 blocks (was 128 on 256 CUs).
//
// Workspace (bytes, MB = 2^20), aliased by liveness:
//   0-8M    combined fp32            (gate gemm; then dead)
//   8-12M   cbf bf16                 (dead after expert GEMM1)
//   12-28M  w1t bf16 [16][1024][512] (dead after GEMM1) / fusedb@12M, obuf@20M after
//   29-61M  w2t bf16 [16][1024][1024](dead after GEMM2)
//   61M     wq / rows / counts
//   63-64M  fw1t bf16 [512][1024]
//   65-97M  h1bf bf16 [16384][1024]
//   99-131M gbuf fp32 (dead after ln_topk) then h2b bf16 [16384][1024]

#define EPSN 1e-5f

typedef __attribute__((ext_vector_type(8))) short v8s;   // 8 bf16 (4 VGPRs)
typedef __attribute__((ext_vector_type(4))) float v4f;   // 4 fp32 acc

typedef const unsigned int __attribute__((address_space(1)))* gas_u32;
typedef unsigned int __attribute__((address_space(3)))* las_u32;

__device__ __forceinline__ void glds16(const void* g, const void* l) {
    __builtin_amdgcn_global_load_lds((gas_u32)(uintptr_t)g, (las_u32)(uintptr_t)l, 16, 0, 0);
}

__device__ __forceinline__ float gelu_f(float x) {
    return 0.5f * x * (1.0f + erff(x * 0.70710678118654752440f));
}
__device__ __forceinline__ unsigned short f2bf(float x) {
    unsigned int u = __float_as_uint(x);
    u += 0x7fffu + ((u >> 16) & 1u);
    return (unsigned short)(u >> 16);
}
__device__ __forceinline__ float bf2f(unsigned short u) {
    return __uint_as_float(((unsigned int)u) << 16);
}

// concat wifi|rfid -> combined fp32, and also emit bf16 copy for MFMA path
__global__ __launch_bounds__(256) void concat_kernel(const float4* __restrict__ wifi,
                                                     const float4* __restrict__ rfid,
                                                     float4* __restrict__ comb,
                                                     ushort4* __restrict__ cbf) {
    int gid = blockIdx.x * 256 + threadIdx.x;   // 4096 * 128
    int b = gid >> 7, c = gid & 127;
    float4 v = (c < 64) ? wifi[b * 64 + c] : rfid[b * 64 + (c - 64)];
    comb[gid] = v;
    ushort4 o;
    o.x = f2bf(v.x); o.y = f2bf(v.y); o.z = f2bf(v.z); o.w = f2bf(v.w);
    cbf[gid] = o;
}

// in: per-expert [K][N] fp32 -> out: per-expert [N][K] bf16 (transpose+convert)
__global__ __launch_bounds__(256) void transpose_f2b(const float* __restrict__ in,
                                                     unsigned short* __restrict__ out,
                                                     int K, int N) {
    __shared__ float t[64][65];
    int e = blockIdx.z;
    int n0 = blockIdx.x << 6, k0 = blockIdx.y << 6;
    const float* ie = in + (long)e * K * N;
    unsigned short* oe = out + (long)e * N * K;
    int tid = threadIdx.x;
    int rr = tid >> 4, cc = (tid & 15) << 2;
#pragma unroll
    for (int p = 0; p < 4; ++p) {
        int k = (p << 4) + rr;
        float4 v = *(const float4*)(ie + (long)(k0 + k) * N + n0 + cc);
        t[k][cc + 0] = v.x; t[k][cc + 1] = v.y; t[k][cc + 2] = v.z; t[k][cc + 3] = v.w;
    }
    __syncthreads();
    int n = tid >> 2, kq = (tid & 3) << 4;
    unsigned short u[16];
#pragma unroll
    for (int j = 0; j < 16; ++j) u[j] = f2bf(t[kq + j][n]);
    uint4* dst = (uint4*)(oe + (long)(n0 + n) * K + k0 + kq);
    dst[0] = ((const uint4*)u)[0];
    dst[1] = ((const uint4*)u)[1];
}

// fp32 gate GEMM: 128x64 tile, BK=16, 256 threads, 8x4/thread. +bias only.
// M=4096, N=1024, K=512 (generic in M/N/K multiples of 128/64/16).
__global__ __launch_bounds__(256) void gate_gemm(
    const float* __restrict__ A, int lda,
    const float* __restrict__ W,
    const float* __restrict__ bias,
    float* __restrict__ out, int ldo, int N, int K)
{
    const int m0 = blockIdx.y << 7;
    const int n0 = blockIdx.x << 6;
    __shared__ float As[16][132];
    __shared__ float Bs[16][68];
    const int tid = threadIdx.x;
    const int ty = tid >> 4, tx = tid & 15;      // ty: 8-row group, tx: 4-col group

    const int arow = tid >> 1;                   // 0..127
    const int akq  = (tid & 1) << 3;             // 0 or 8
    const float* Aptr = A + (long)(m0 + arow) * lda + akq;
    const int bkr = tid >> 4;                    // 0..15 (k)
    const int bnq = (tid & 15) << 2;             // 0..60 (n)
    const float* Bptr = W + (long)bkr * N + n0 + bnq;

    float acc[8][4] = {};
    for (int k0 = 0; k0 < K; k0 += 16) {
        float4 a0 = *(const float4*)(Aptr + k0);
        float4 a1 = *(const float4*)(Aptr + k0 + 4);
        float4 bv = *(const float4*)(Bptr + (long)k0 * N);
        As[akq + 0][arow] = a0.x; As[akq + 1][arow] = a0.y;
        As[akq + 2][arow] = a0.z; As[akq + 3][arow] = a0.w;
        As[akq + 4][arow] = a1.x; As[akq + 5][arow] = a1.y;
        As[akq + 6][arow] = a1.z; As[akq + 7][arow] = a1.w;
        *(float4*)&Bs[bkr][bnq] = bv;
        __syncthreads();
#pragma unroll
        for (int kk = 0; kk < 16; ++kk) {
            float4 af0 = *(const float4*)&As[kk][ty << 3];
            float4 af1 = *(const float4*)&As[kk][(ty << 3) + 4];
            float4 bf = *(const float4*)&Bs[kk][tx << 2];
            const float a8[8] = {af0.x, af0.y, af0.z, af0.w, af1.x, af1.y, af1.z, af1.w};
            const float b4[4] = {bf.x, bf.y, bf.z, bf.w};
#pragma unroll
            for (int i = 0; i < 8; ++i)
#pragma unroll
                for (int j = 0; j < 4; ++j)
                    acc[i][j] = fmaf(a8[i], b4[j], acc[i][j]);
        }
        __syncthreads();
    }
#pragma unroll
    for (int i = 0; i < 8; ++i) {
        int r = m0 + (ty << 3) + i;
        int c0 = n0 + (tx << 2);
        float4 v;
        v.x = acc[i][0] + bias[c0 + 0];
        v.y = acc[i][1] + bias[c0 + 1];
        v.z = acc[i][2] + bias[c0 + 2];
        v.w = acc[i][3] + bias[c0 + 3];
        *(float4*)(out + (long)r * ldo + c0) = v;
    }
}

// Fused: LayerNorm+GELU (row of 1024) -> gate logits (16) -> softmax -> top4
// -> renorm softmax -> scatter (rows/counts/weights). One block per row.
__global__ __launch_bounds__(256) void ln_topk_kernel(
    const float* __restrict__ g,
    const float* __restrict__ lng, const float* __restrict__ lnb,
    const float* __restrict__ w2, const float* __restrict__ b2,
    float* __restrict__ wout, int* __restrict__ rows_, int* __restrict__ counts)
{
    __shared__ float gs[1024];
    __shared__ float red[16][17];
    __shared__ float rs[4], rq[4];
    const int b = blockIdx.x;
    const int tid = threadIdx.x;
    const int c = tid << 2;

    float4 v = *(const float4*)(g + (long)b * 1024 + c);
    float s = v.x + v.y + v.z + v.w;
    float q = v.x * v.x + v.y * v.y + v.z * v.z + v.w * v.w;
    for (int off = 32; off > 0; off >>= 1) {
        s += __shfl_down(s, off);
        q += __shfl_down(q, off);
    }
    int wid = tid >> 6;
    if ((tid & 63) == 0) { rs[wid] = s; rq[wid] = q; }
    __syncthreads();
    float S = rs[0] + rs[1] + rs[2] + rs[3];
    float Q = rq[0] + rq[1] + rq[2] + rq[3];
    float mu = S * (1.0f / 1024.0f);
    float var = Q * (1.0f / 1024.0f) - mu * mu;
    float rstd = rsqrtf(var + EPSN);
    gs[c + 0] = gelu_f((v.x - mu) * rstd * lng[c + 0] + lnb[c + 0]);
    gs[c + 1] = gelu_f((v.y - mu) * rstd * lng[c + 1] + lnb[c + 1]);
    gs[c + 2] = gelu_f((v.z - mu) * rstd * lng[c + 2] + lnb[c + 2]);
    gs[c + 3] = gelu_f((v.w - mu) * rstd * lng[c + 3] + lnb[c + 3]);
    __syncthreads();

    const int e = tid & 15, chunk = tid >> 4;
    float p = 0.f;
#pragma unroll 8
    for (int i = 0; i < 64; ++i) {
        int idx = (chunk << 6) + i;
        p = fmaf(gs[idx], w2[(idx << 4) + e], p);
    }
    red[chunk][e] = p;
    __syncthreads();

    if (tid < 64) {
        float logit = -1e30f;
        if (tid < 16) {
            logit = b2[tid];
#pragma unroll
            for (int cc = 0; cc < 16; ++cc) logit += red[cc][tid];
        }
        float m = logit;
#pragma unroll
        for (int mk = 8; mk >= 1; mk >>= 1) m = fmaxf(m, __shfl_xor(m, mk));
        float pe = (tid < 16) ? expf(logit - m) : 0.f;
        float Z = pe;
#pragma unroll
        for (int mk = 8; mk >= 1; mk >>= 1) Z += __shfl_xor(Z, mk);
        float prob = pe / Z;

        float cur = (tid < 16) ? prob : -1.f;
        const int myi = tid & 15;
        float tv0, tv1, tv2, tv3;
        int ti0, ti1, ti2, ti3;
#define ARGMAX16(TV, TI)                                                     \
        {   float vv = cur; int ii = myi;                                    \
            _Pragma("unroll")                                                \
            for (int mk = 8; mk >= 1; mk >>= 1) {                            \
                float ov = __shfl_xor(vv, mk); int oi = __shfl_xor(ii, mk);  \
                if (ov > vv || (ov == vv && oi < ii)) { vv = ov; ii = oi; }  \
            }                                                                \
            TV = vv; TI = ii;                                                \
            if (myi == ii) cur = -1.f;                                       \
        }
        ARGMAX16(tv0, ti0)
        ARGMAX16(tv1, ti1)
        ARGMAX16(tv2, ti2)
        ARGMAX16(tv3, ti3)
#undef ARGMAX16

        float q0 = 1.f;
        float q1 = expf(tv1 - tv0);
        float q2 = expf(tv2 - tv0);
        float q3 = expf(tv3 - tv0);
        float iZ2 = 1.f / (q0 + q1 + q2 + q3);
        if (tid < 4) {
            float wk = (tid == 0) ? q0 : (tid == 1) ? q1 : (tid == 2) ? q2 : q3;
            int   ee = (tid == 0) ? ti0 : (tid == 1) ? ti1 : (tid == 2) ? ti2 : ti3;
            wout[(b << 2) + tid] = wk * iZ2;
            int j = atomicAdd(&counts[ee], 1);
            rows_[(ee << 12) + j] = (b << 2) | tid;
        }
    }
}

// bf16 MFMA GEMM: TMx128 tile, BK=32, 256 threads (4 waves 2x2).
// Grid: x = n-chunk (128), y = expert, z = m-chunk (TM)  [spreads working
// blocks across all CUs when gathered cnt << M].
template<int TM, int ASHIFT, bool GATHER, bool OUTBF>
__global__ __launch_bounds__(256) void mfma_gemm(
    const unsigned short* __restrict__ A, int K,
    const unsigned short* __restrict__ Wt, long wstride,
    const float* __restrict__ bias,
    const float* __restrict__ bng, const float* __restrict__ bnb,
    const float* __restrict__ bnm, const float* __restrict__ bnv,
    int pstride,
    void* __restrict__ outv, int ldo,
    const int* __restrict__ rows_, const int* __restrict__ counts, int M)
{
    const int e  = blockIdx.y;
    const int m0 = blockIdx.z * TM;
    const int n0 = blockIdx.x << 7;
    const int cnt = GATHER ? counts[e] : M;
    if (m0 >= cnt) return;

    __shared__ unsigned short Als[TM * 32];   // [row][k] 64B rows
    __shared__ unsigned short Bls[128 * 32];  // [n][k]
    __shared__ int rid[TM];
    __shared__ int ain[TM];

    const int tid = threadIdx.x;
    if (tid < TM) {
        int i = m0 + tid;
        int pk, ai;
        if (GATHER) {
            if (i < cnt) { pk = rows_[(e << 12) + i]; ai = pk >> ASHIFT; }
            else { pk = -1; ai = 0; }
        } else { pk = i; ai = i; }
        rid[tid] = pk;
        ain[tid] = ai;
    }
    __syncthreads();

    const int wave = tid >> 6, lane = tid & 63;
    const int wm = (wave >> 1) * (TM >> 1), wn = (wave & 1) << 6;
    const int lrow = lane & 15, kch = lane >> 4;
    constexpr int MF = TM >> 5;               // m-fragments per wave

    const int r0 = ain[tid >> 2];
    const unsigned short* ap0 = A + (long)r0 * K + ((tid & 3) << 3);
    const unsigned short* ap1 = nullptr;
    if (TM == 128)
        ap1 = A + (long)ain[64 + (tid >> 2)] * K + ((tid & 3) << 3);
    const unsigned short* Wte = Wt + (long)e * wstride;
    const unsigned short* bp0 = Wte + (long)(n0 + (tid >> 2)) * K + ((tid & 3) << 3);
    const unsigned short* bp1 = Wte + (long)(n0 + 64 + (tid >> 2)) * K + ((tid & 3) << 3);

    v4f acc[MF][4] = {};

    const int nk = K >> 5;
    for (int it = 0; it < nk; ++it) {
        glds16(ap0, Als + (wave << 9));
        if (TM == 128) glds16(ap1, Als + 2048 + (wave << 9));
        glds16(bp0, Bls + (wave << 9));
        glds16(bp1, Bls + 2048 + (wave << 9));
        ap0 += 32; if (TM == 128) ap1 += 32;
        bp0 += 32; bp1 += 32;
        __syncthreads();

        v8s av[MF], bv[4];
#pragma unroll
        for (int f = 0; f < MF; ++f)
            av[f] = *(const v8s*)(Als + ((wm + (f << 4) + lrow) << 5) + (kch << 3));
#pragma unroll
        for (int f = 0; f < 4; ++f)
            bv[f] = *(const v8s*)(Bls + ((wn + (f << 4) + lrow) << 5) + (kch << 3));
#pragma unroll
        for (int fi = 0; fi < MF; ++fi)
#pragma unroll
            for (int fj = 0; fj < 4; ++fj)
                acc[fi][fj] = __builtin_amdgcn_mfma_f32_16x16x32_bf16(
                    av[fi], bv[fj], acc[fi][fj], 0, 0, 0);
        __syncthreads();
    }

    // epilogue: C/D layout col=lane&15, row=(lane>>4)*4+reg
#pragma unroll
    for (int fj = 0; fj < 4; ++fj) {
        const int c = n0 + wn + (fj << 4) + lrow;
        const int pc = e * pstride + c;
        const float bs = bias[pc];
        const float sc = bng[pc] * rsqrtf(bnv[pc] + EPSN);
        const float mn = bnm[pc], bb = bnb[pc];
#pragma unroll
        for (int fi = 0; fi < MF; ++fi) {
#pragma unroll
            for (int r = 0; r < 4; ++r) {
                const int lr = wm + (fi << 4) + (kch << 2) + r;
                const int orow = rid[lr];
                if (orow < 0) continue;
                float x = acc[fi][fj][r] + bs;
                x = (x - mn) * sc + bb;
                x = gelu_f(x);
                if (OUTBF)
                    ((unsigned short*)outv)[(long)orow * ldo + c] = f2bf(x);
                else
                    ((float*)outv)[(long)orow * ldo + c] = x;
            }
        }
    }
}

// weighted top-4 combine, bf16 in -> bf16 out
__global__ __launch_bounds__(256) void combine_bf_kernel(const ushort4* __restrict__ h2b,
                                                         const float* __restrict__ w,
                                                         ushort4* __restrict__ fusedb) {
    int gid = blockIdx.x * 256 + threadIdx.x;  // 4096*256
    int b = gid >> 8, c = gid & 255;
    float a0 = 0.f, a1 = 0.f, a2 = 0.f, a3 = 0.f;
#pragma unroll
    for (int k = 0; k < 4; ++k) {
        float wk = w[b * 4 + k];
        ushort4 v = h2b[(long)(b * 4 + k) * 256 + c];
        a0 += wk * bf2f(v.x); a1 += wk * bf2f(v.y);
        a2 += wk * bf2f(v.z); a3 += wk * bf2f(v.w);
    }
    ushort4 o;
    o.x = f2bf(a0); o.y = f2bf(a1); o.z = f2bf(a2); o.w = f2bf(a3);
    fusedb[gid] = o;
}

__global__ __launch_bounds__(256) void fin2_kernel(const float* __restrict__ o,
                                                   const float* __restrict__ w2,
                                                   const float* __restrict__ b2,
                                                   float* __restrict__ out) {
    __shared__ float ws[512 * 20];
    int tid = threadIdx.x;
    for (int i = tid; i < 512 * 20; i += 256) ws[i] = w2[i];
    __syncthreads();
    int r = blockIdx.x * 64 + (tid >> 2);
    int c0 = (tid & 3) * 5;
    float acc[5];
#pragma unroll
    for (int j = 0; j < 5; ++j) acc[j] = b2[c0 + j];
    const float* orow = o + (long)r * 512;
    for (int i = 0; i < 512; ++i) {
        float v = orow[i];
#pragma unroll
        for (int j = 0; j < 5; ++j) acc[j] += v * ws[i * 20 + c0 + j];
    }
#pragma unroll
    for (int j = 0; j < 5; ++j) out[r * 20 + c0 + j] = acc[j];
}

extern "C" void kernel_launch(void* const* d_in, const int* in_sizes, int n_in,
                              void* d_out, int out_size, void* d_ws, size_t ws_size,
                              hipStream_t stream) {
    const float* wifi    = (const float*)d_in[0];
    const float* rfid    = (const float*)d_in[1];
    const float* gate_w1 = (const float*)d_in[2];
    const float* gate_b1 = (const float*)d_in[3];
    const float* gln_g   = (const float*)d_in[4];
    const float* gln_b   = (const float*)d_in[5];
    const float* gate_w2 = (const float*)d_in[6];
    const float* gate_b2 = (const float*)d_in[7];
    const float* exp_w1  = (const float*)d_in[8];
    const float* exp_b1  = (const float*)d_in[9];
    const float* bn1g    = (const float*)d_in[10];
    const float* bn1b    = (const float*)d_in[11];
    const float* bn1m    = (const float*)d_in[12];
    const float* bn1v    = (const float*)d_in[13];
    const float* exp_w2  = (const float*)d_in[14];
    const float* exp_b2  = (const float*)d_in[15];
    const float* bn2g    = (const float*)d_in[16];
    const float* bn2b    = (const float*)d_in[17];
    const float* bn2m    = (const float*)d_in[18];
    const float* bn2v    = (const float*)d_in[19];
    const float* fin_w1  = (const float*)d_in[20];
    const float* fin_b1  = (const float*)d_in[21];
    const float* fbng    = (const float*)d_in[22];
    const float* fbnb    = (const float*)d_in[23];
    const float* fbnm    = (const float*)d_in[24];
    const float* fbnv    = (const float*)d_in[25];
    const float* fin_w2  = (const float*)d_in[26];
    const float* fin_b2  = (const float*)d_in[27];
    float* out = (float*)d_out;

    const size_t MBy = 1u << 20;
    char* W = (char*)d_ws;
    float*          combined = (float*)         (W + 0);
    unsigned short* cbf      = (unsigned short*)(W + 8 * MBy);
    unsigned short* w1t      = (unsigned short*)(W + 12 * MBy);
    unsigned short* fusedb   = (unsigned short*)(W + 12 * MBy);   // after w1t dead
    float*          obuf     = (float*)         (W + 20 * MBy);   // after w1t dead
    unsigned short* w2t      = (unsigned short*)(W + 29 * MBy);
    float*          wq       = (float*)         (W + 61 * MBy);
    int*            rows     = (int*)           (W + 61 * MBy + (1 << 16));
    int*            counts   = (int*)           (W + 61 * MBy + (1 << 16) + (1 << 18));
    unsigned short* fw1t     = (unsigned short*)(W + 63 * MBy);
    unsigned short* h1bf     = (unsigned short*)(W + 65 * MBy);
    float*          gbuf     = (float*)         (W + 99 * MBy);
    unsigned short* h2b      = (unsigned short*)(W + 99 * MBy);   // after gbuf dead

    hipMemsetAsync(counts, 0, 16 * sizeof(int), stream);

    concat_kernel<<<2048, 256, 0, stream>>>((const float4*)wifi, (const float4*)rfid,
                                            (float4*)combined, (ushort4*)cbf);

    // weight transposes fp32 [K][N] -> bf16 [N][K]
    transpose_f2b<<<dim3(16, 8, 16), 256, 0, stream>>>(exp_w1, w1t, 512, 1024);
    transpose_f2b<<<dim3(16, 16, 16), 256, 0, stream>>>(exp_w2, w2t, 1024, 1024);
    transpose_f2b<<<dim3(8, 16, 1), 256, 0, stream>>>(fin_w1, fw1t, 1024, 512);

    // gate (fp32): GEMM1 -> fused LN/GELU/logits/softmax/top4
    gate_gemm<<<dim3(16, 32, 1), 256, 0, stream>>>(combined, 512, gate_w1, gate_b1,
                                                   gbuf, 1024, 1024, 512);
    ln_topk_kernel<<<4096, 256, 0, stream>>>(gbuf, gln_g, gln_b, gate_w2, gate_b2,
                                             wq, rows, counts);

    // expert GEMM1 (gathered, bf16 MFMA): cbf rows -> h1bf[slot]
    mfma_gemm<128, 2, true, true><<<dim3(8, 16, 32), 256, 0, stream>>>(
        cbf, 512, w1t, (long)512 * 1024, exp_b1,
        bn1g, bn1b, bn1m, bn1v, 1024,
        h1bf, 1024, rows, counts, 4096);

    // expert GEMM2 (gathered, bf16 MFMA): h1bf[slot] -> h2b[slot]
    mfma_gemm<128, 0, true, true><<<dim3(8, 16, 32), 256, 0, stream>>>(
        h1bf, 1024, w2t, (long)1024 * 1024, exp_b2,
        bn2g, bn2b, bn2m, bn2v, 1024,
        h2b, 1024, rows, counts, 4096);

    combine_bf_kernel<<<4096, 256, 0, stream>>>((const ushort4*)h2b, wq, (ushort4*)fusedb);

    // final GEMM1 (bf16 MFMA, TM=64 -> 256 blocks): fusedb -> obuf fp32, BN+GELU
    mfma_gemm<64, 0, false, false><<<dim3(4, 1, 64), 256, 0, stream>>>(
        fusedb, 1024, fw1t, 0, fin_b1,
        fbng, fbnb, fbnm, fbnv, 0,
        obuf, 512, nullptr, nullptr, 4096);

    fin2_kernel<<<64, 256, 0, stream>>>(obuf, fin_w2, fin_b2, out);
}

// Round 6
// 501.415 us; speedup vs baseline: 2.6406x; 1.0865x over previous
//
#include <hip/hip_runtime.h>

// MoE_77644418777543 — round 4 (resubmit; r4 bench was an infra failure).
// r3 post-mortem: grid reorder changed nothing (occ 21%, 111us) -> not CU
// placement. Limiter = ~4 working blocks/CU (75% empty launches) on a
// load->barrier->compute chain + 2-byte scattered epilogue stores (RMW,
// WRITE 57MB vs 32 ideal). Fixes: (1) worklist-driven grid (exact work,
// <=271 items, static 8x272); (2) TM=64 tiles -> ~8 working blocks/CU;
// (3) LDS-staged epilogue -> 16B vectorized stores.
//
// Workspace (MB = 2^20), aliased by liveness:
//   0-8M    combined fp32            (gate gemm; then dead)
//   8-12M   cbf bf16                 (dead after expert GEMM1)
//   12-28M  w1t bf16 [16][1024][512] (dead after GEMM1) / fusedb@12M, obuf@20M after
//   29-61M  w2t bf16 [16][1024][1024](dead after GEMM2)
//   61M     wq / rows / counts / worklist
//   63-64M  fw1t bf16 [512][1024]
//   65-97M  h1bf bf16 [16384][1024]
//   99-131M gbuf fp32 (dead after ln_topk) then h2b bf16 [16384][1024]

#define EPSN 1e-5f

typedef __attribute__((ext_vector_type(8))) short v8s;   // 8 bf16 (4 VGPRs)
typedef __attribute__((ext_vector_type(4))) float v4f;   // 4 fp32 acc

typedef const unsigned int __attribute__((address_space(1)))* gas_u32;
typedef unsigned int __attribute__((address_space(3)))* las_u32;

__device__ __forceinline__ void glds16(const void* g, const void* l) {
    __builtin_amdgcn_global_load_lds((gas_u32)(uintptr_t)g, (las_u32)(uintptr_t)l, 16, 0, 0);
}

__device__ __forceinline__ float gelu_f(float x) {
    return 0.5f * x * (1.0f + erff(x * 0.70710678118654752440f));
}
__device__ __forceinline__ unsigned short f2bf(float x) {
    unsigned int u = __float_as_uint(x);
    u += 0x7fffu + ((u >> 16) & 1u);
    return (unsigned short)(u >> 16);
}
__device__ __forceinline__ float bf2f(unsigned short u) {
    return __uint_as_float(((unsigned int)u) << 16);
}

// concat wifi|rfid -> combined fp32, and also emit bf16 copy for MFMA path
__global__ __launch_bounds__(256) void concat_kernel(const float4* __restrict__ wifi,
                                                     const float4* __restrict__ rfid,
                                                     float4* __restrict__ comb,
                                                     ushort4* __restrict__ cbf) {
    int gid = blockIdx.x * 256 + threadIdx.x;   // 4096 * 128
    int b = gid >> 7, c = gid & 127;
    float4 v = (c < 64) ? wifi[b * 64 + c] : rfid[b * 64 + (c - 64)];
    comb[gid] = v;
    ushort4 o;
    o.x = f2bf(v.x); o.y = f2bf(v.y); o.z = f2bf(v.z); o.w = f2bf(v.w);
    cbf[gid] = o;
}

// in: per-expert [K][N] fp32 -> out: per-expert [N][K] bf16 (transpose+convert)
__global__ __launch_bounds__(256) void transpose_f2b(const float* __restrict__ in,
                                                     unsigned short* __restrict__ out,
                                                     int K, int N) {
    __shared__ float t[64][65];
    int e = blockIdx.z;
    int n0 = blockIdx.x << 6, k0 = blockIdx.y << 6;
    const float* ie = in + (long)e * K * N;
    unsigned short* oe = out + (long)e * N * K;
    int tid = threadIdx.x;
    int rr = tid >> 4, cc = (tid & 15) << 2;
#pragma unroll
    for (int p = 0; p < 4; ++p) {
        int k = (p << 4) + rr;
        float4 v = *(const float4*)(ie + (long)(k0 + k) * N + n0 + cc);
        t[k][cc + 0] = v.x; t[k][cc + 1] = v.y; t[k][cc + 2] = v.z; t[k][cc + 3] = v.w;
    }
    __syncthreads();
    int n = tid >> 2, kq = (tid & 3) << 4;
    unsigned short u[16];
#pragma unroll
    for (int j = 0; j < 16; ++j) u[j] = f2bf(t[kq + j][n]);
    uint4* dst = (uint4*)(oe + (long)(n0 + n) * K + k0 + kq);
    dst[0] = ((const uint4*)u)[0];
    dst[1] = ((const uint4*)u)[1];
}

// fp32 gate GEMM: 128x64 tile, BK=16, 256 threads, 8x4/thread. +bias only.
__global__ __launch_bounds__(256) void gate_gemm(
    const float* __restrict__ A, int lda,
    const float* __restrict__ W,
    const float* __restrict__ bias,
    float* __restrict__ out, int ldo, int N, int K)
{
    const int m0 = blockIdx.y << 7;
    const int n0 = blockIdx.x << 6;
    __shared__ float As[16][132];
    __shared__ float Bs[16][68];
    const int tid = threadIdx.x;
    const int ty = tid >> 4, tx = tid & 15;

    const int arow = tid >> 1;
    const int akq  = (tid & 1) << 3;
    const float* Aptr = A + (long)(m0 + arow) * lda + akq;
    const int bkr = tid >> 4;
    const int bnq = (tid & 15) << 2;
    const float* Bptr = W + (long)bkr * N + n0 + bnq;

    float acc[8][4] = {};
    for (int k0 = 0; k0 < K; k0 += 16) {
        float4 a0 = *(const float4*)(Aptr + k0);
        float4 a1 = *(const float4*)(Aptr + k0 + 4);
        float4 bv = *(const float4*)(Bptr + (long)k0 * N);
        As[akq + 0][arow] = a0.x; As[akq + 1][arow] = a0.y;
        As[akq + 2][arow] = a0.z; As[akq + 3][arow] = a0.w;
        As[akq + 4][arow] = a1.x; As[akq + 5][arow] = a1.y;
        As[akq + 6][arow] = a1.z; As[akq + 7][arow] = a1.w;
        *(float4*)&Bs[bkr][bnq] = bv;
        __syncthreads();
#pragma unroll
        for (int kk = 0; kk < 16; ++kk) {
            float4 af0 = *(const float4*)&As[kk][ty << 3];
            float4 af1 = *(const float4*)&As[kk][(ty << 3) + 4];
            float4 bf = *(const float4*)&Bs[kk][tx << 2];
            const float a8[8] = {af0.x, af0.y, af0.z, af0.w, af1.x, af1.y, af1.z, af1.w};
            const float b4[4] = {bf.x, bf.y, bf.z, bf.w};
#pragma unroll
            for (int i = 0; i < 8; ++i)
#pragma unroll
                for (int j = 0; j < 4; ++j)
                    acc[i][j] = fmaf(a8[i], b4[j], acc[i][j]);
        }
        __syncthreads();
    }
#pragma unroll
    for (int i = 0; i < 8; ++i) {
        int r = m0 + (ty << 3) + i;
        int c0 = n0 + (tx << 2);
        float4 v;
        v.x = acc[i][0] + bias[c0 + 0];
        v.y = acc[i][1] + bias[c0 + 1];
        v.z = acc[i][2] + bias[c0 + 2];
        v.w = acc[i][3] + bias[c0 + 3];
        *(float4*)(out + (long)r * ldo + c0) = v;
    }
}

// Fused: LayerNorm+GELU (row of 1024) -> gate logits (16) -> softmax -> top4
// -> renorm softmax -> scatter (rows/counts/weights). One block per row.
__global__ __launch_bounds__(256) void ln_topk_kernel(
    const float* __restrict__ g,
    const float* __restrict__ lng, const float* __restrict__ lnb,
    const float* __restrict__ w2, const float* __restrict__ b2,
    float* __restrict__ wout, int* __restrict__ rows_, int* __restrict__ counts)
{
    __shared__ float gs[1024];
    __shared__ float red[16][17];
    __shared__ float rs[4], rq[4];
    const int b = blockIdx.x;
    const int tid = threadIdx.x;
    const int c = tid << 2;

    float4 v = *(const float4*)(g + (long)b * 1024 + c);
    float s = v.x + v.y + v.z + v.w;
    float q = v.x * v.x + v.y * v.y + v.z * v.z + v.w * v.w;
    for (int off = 32; off > 0; off >>= 1) {
        s += __shfl_down(s, off);
        q += __shfl_down(q, off);
    }
    int wid = tid >> 6;
    if ((tid & 63) == 0) { rs[wid] = s; rq[wid] = q; }
    __syncthreads();
    float S = rs[0] + rs[1] + rs[2] + rs[3];
    float Q = rq[0] + rq[1] + rq[2] + rq[3];
    float mu = S * (1.0f / 1024.0f);
    float var = Q * (1.0f / 1024.0f) - mu * mu;
    float rstd = rsqrtf(var + EPSN);
    gs[c + 0] = gelu_f((v.x - mu) * rstd * lng[c + 0] + lnb[c + 0]);
    gs[c + 1] = gelu_f((v.y - mu) * rstd * lng[c + 1] + lnb[c + 1]);
    gs[c + 2] = gelu_f((v.z - mu) * rstd * lng[c + 2] + lnb[c + 2]);
    gs[c + 3] = gelu_f((v.w - mu) * rstd * lng[c + 3] + lnb[c + 3]);
    __syncthreads();

    const int e = tid & 15, chunk = tid >> 4;
    float p = 0.f;
#pragma unroll 8
    for (int i = 0; i < 64; ++i) {
        int idx = (chunk << 6) + i;
        p = fmaf(gs[idx], w2[(idx << 4) + e], p);
    }
    red[chunk][e] = p;
    __syncthreads();

    if (tid < 64) {
        float logit = -1e30f;
        if (tid < 16) {
            logit = b2[tid];
#pragma unroll
            for (int cc = 0; cc < 16; ++cc) logit += red[cc][tid];
        }
        float m = logit;
#pragma unroll
        for (int mk = 8; mk >= 1; mk >>= 1) m = fmaxf(m, __shfl_xor(m, mk));
        float pe = (tid < 16) ? expf(logit - m) : 0.f;
        float Z = pe;
#pragma unroll
        for (int mk = 8; mk >= 1; mk >>= 1) Z += __shfl_xor(Z, mk);
        float prob = pe / Z;

        float cur = (tid < 16) ? prob : -1.f;
        const int myi = tid & 15;
        float tv0, tv1, tv2, tv3;
        int ti0, ti1, ti2, ti3;
#define ARGMAX16(TV, TI)                                                     \
        {   float vv = cur; int ii = myi;                                    \
            _Pragma("unroll")                                                \
            for (int mk = 8; mk >= 1; mk >>= 1) {                            \
                float ov = __shfl_xor(vv, mk); int oi = __shfl_xor(ii, mk);  \
                if (ov > vv || (ov == vv && oi < ii)) { vv = ov; ii = oi; }  \
            }                                                                \
            TV = vv; TI = ii;                                                \
            if (myi == ii) cur = -1.f;                                       \
        }
        ARGMAX16(tv0, ti0)
        ARGMAX16(tv1, ti1)
        ARGMAX16(tv2, ti2)
        ARGMAX16(tv3, ti3)
#undef ARGMAX16

        float q0 = 1.f;
        float q1 = expf(tv1 - tv0);
        float q2 = expf(tv2 - tv0);
        float q3 = expf(tv3 - tv0);
        float iZ2 = 1.f / (q0 + q1 + q2 + q3);
        if (tid < 4) {
            float wk = (tid == 0) ? q0 : (tid == 1) ? q1 : (tid == 2) ? q2 : q3;
            int   ee = (tid == 0) ? ti0 : (tid == 1) ? ti1 : (tid == 2) ? ti2 : ti3;
            wout[(b << 2) + tid] = wk * iZ2;
            int j = atomicAdd(&counts[ee], 1);
            rows_[(ee << 12) + j] = (b << 2) | tid;
        }
    }
}

// Build exact work list of (expert<<16 | m_chunk) for TM=64 tiles.
// Sum over experts of ceil(cnt/64) <= 271 (Sum cnt = 16384). Sentinel -1.
#define WL_MAX 272
__global__ __launch_bounds__(256) void build_wl_kernel(const int* __restrict__ counts,
                                                       int* __restrict__ wl) {
    int t = threadIdx.x;
    for (int i = t; i < WL_MAX; i += 256) wl[i] = -1;
    __syncthreads();
    if (t == 0) {
        int idx = 0;
        for (int e = 0; e < 16; ++e) {
            int nc = (counts[e] + 63) >> 6;
            for (int c = 0; c < nc; ++c) wl[idx++] = (e << 16) | c;
        }
    }
}

// bf16 MFMA GEMM: TMx128 tile, BK=32, 256 threads (4 waves 2x2).
// WL: grid (x=n-chunk, y=work-item) driven by worklist (gathered experts).
// !WL: grid (x=n-chunk, y=1, z=m-chunk), dense.
// OUTBF epilogue: BN+GELU -> bf16 LDS tile -> vectorized 16B row stores.
template<int TM, int ASHIFT, bool GATHER, bool OUTBF, bool WL>
__global__ __launch_bounds__(256) void mfma_gemm(
    const unsigned short* __restrict__ A, int K,
    const unsigned short* __restrict__ Wt, long wstride,
    const float* __restrict__ bias,
    const float* __restrict__ bng, const float* __restrict__ bnb,
    const float* __restrict__ bnm, const float* __restrict__ bnv,
    int pstride,
    void* __restrict__ outv, int ldo,
    const int* __restrict__ rows_, const int* __restrict__ counts,
    const int* __restrict__ wl, int M)
{
    int e, m0;
    if (WL) {
        int w = wl[blockIdx.y];
        if (w < 0) return;
        e = w >> 16;
        m0 = (w & 0xffff) << 6;
    } else {
        e = blockIdx.y;
        m0 = blockIdx.z * TM;
    }
    const int n0 = blockIdx.x << 7;
    const int cnt = GATHER ? counts[e] : M;

    constexpr int AB_USH = TM * 32 + 128 * 32;          // stage: A + B
    constexpr int OL_STRIDE = 136;                      // 272 B rows (16B-aligned)
    constexpr int OL_USH = OUTBF ? TM * OL_STRIDE : 0;  // out staging (reuses stage)
    constexpr int SM_USH = (OL_USH > AB_USH) ? OL_USH : AB_USH;
    __shared__ __align__(16) unsigned short smem[SM_USH];
    unsigned short* Als = smem;            // [TM][32]
    unsigned short* Bls = smem + TM * 32;  // [128][32]
    __shared__ int rid[TM];
    __shared__ int ain[TM];

    const int tid = threadIdx.x;
    if (tid < TM) {
        int i = m0 + tid;
        int pk, ai;
        if (GATHER) {
            if (i < cnt) { pk = rows_[(e << 12) + i]; ai = pk >> ASHIFT; }
            else { pk = -1; ai = 0; }
        } else { pk = i; ai = i; }
        rid[tid] = pk;
        ain[tid] = ai;
    }
    __syncthreads();

    const int wave = tid >> 6, lane = tid & 63;
    const int wm = (wave >> 1) * (TM >> 1), wn = (wave & 1) << 6;
    const int lrow = lane & 15, kch = lane >> 4;
    constexpr int MF = TM >> 5;               // m-fragments per wave

    const int r0 = ain[tid >> 2];
    const unsigned short* ap0 = A + (long)r0 * K + ((tid & 3) << 3);
    const unsigned short* ap1 = nullptr;
    if constexpr (TM == 128)
        ap1 = A + (long)ain[64 + (tid >> 2)] * K + ((tid & 3) << 3);
    const unsigned short* Wte = Wt + (long)e * wstride;
    const unsigned short* bp0 = Wte + (long)(n0 + (tid >> 2)) * K + ((tid & 3) << 3);
    const unsigned short* bp1 = Wte + (long)(n0 + 64 + (tid >> 2)) * K + ((tid & 3) << 3);

    v4f acc[MF][4] = {};

    const int nk = K >> 5;
    for (int it = 0; it < nk; ++it) {
        glds16(ap0, Als + (wave << 9));
        if constexpr (TM == 128) glds16(ap1, Als + 2048 + (wave << 9));
        glds16(bp0, Bls + (wave << 9));
        glds16(bp1, Bls + 2048 + (wave << 9));
        ap0 += 32;
        if constexpr (TM == 128) ap1 += 32;
        bp0 += 32; bp1 += 32;
        __syncthreads();

        v8s av[MF], bv[4];
#pragma unroll
        for (int f = 0; f < MF; ++f)
            av[f] = *(const v8s*)(Als + ((wm + (f << 4) + lrow) << 5) + (kch << 3));
#pragma unroll
        for (int f = 0; f < 4; ++f)
            bv[f] = *(const v8s*)(Bls + ((wn + (f << 4) + lrow) << 5) + (kch << 3));
#pragma unroll
        for (int fi = 0; fi < MF; ++fi)
#pragma unroll
            for (int fj = 0; fj < 4; ++fj)
                acc[fi][fj] = __builtin_amdgcn_mfma_f32_16x16x32_bf16(
                    av[fi], bv[fj], acc[fi][fj], 0, 0, 0);
        __syncthreads();
    }

    // epilogue: C/D layout col=lane&15, row=(lane>>4)*4+reg
    if constexpr (OUTBF) {
        // stage BN+GELU'd bf16 tile in LDS (stage buffers dead after last barrier)
        unsigned short* Ols = smem;
#pragma unroll
        for (int fj = 0; fj < 4; ++fj) {
            const int c = wn + (fj << 4) + lrow;
            const int pc = e * pstride + n0 + c;
            const float bs = bias[pc];
            const float sc = bng[pc] * rsqrtf(bnv[pc] + EPSN);
            const float mn = bnm[pc], bb = bnb[pc];
#pragma unroll
            for (int fi = 0; fi < MF; ++fi) {
#pragma unroll
                for (int r = 0; r < 4; ++r) {
                    const int lr = wm + (fi << 4) + (kch << 2) + r;
                    float x = acc[fi][fj][r] + bs;
                    x = (x - mn) * sc + bb;
                    x = gelu_f(x);
                    Ols[lr * OL_STRIDE + c] = f2bf(x);
                }
            }
        }
        __syncthreads();
        // cooperative vectorized stores: 16 rows/pass, 16B per lane
        const int rl = tid >> 4;
        const int c8 = (tid & 15) << 3;
#pragma unroll
        for (int p = 0; p < TM / 16; ++p) {
            const int row = (p << 4) + rl;
            const int orow = rid[row];
            if (orow >= 0) {
                uint4 v = *(const uint4*)(Ols + row * OL_STRIDE + c8);
                *(uint4*)((unsigned short*)outv + (long)orow * ldo + n0 + c8) = v;
            }
        }
    } else {
#pragma unroll
        for (int fj = 0; fj < 4; ++fj) {
            const int c = n0 + wn + (fj << 4) + lrow;
            const int pc = e * pstride + c;
            const float bs = bias[pc];
            const float sc = bng[pc] * rsqrtf(bnv[pc] + EPSN);
            const float mn = bnm[pc], bb = bnb[pc];
#pragma unroll
            for (int fi = 0; fi < MF; ++fi) {
#pragma unroll
                for (int r = 0; r < 4; ++r) {
                    const int lr = wm + (fi << 4) + (kch << 2) + r;
                    const int orow = rid[lr];
                    if (orow < 0) continue;
                    float x = acc[fi][fj][r] + bs;
                    x = (x - mn) * sc + bb;
                    x = gelu_f(x);
                    ((float*)outv)[(long)orow * ldo + c] = x;
                }
            }
        }
    }
}

// weighted top-4 combine, bf16 in -> bf16 out
__global__ __launch_bounds__(256) void combine_bf_kernel(const ushort4* __restrict__ h2b,
                                                         const float* __restrict__ w,
                                                         ushort4* __restrict__ fusedb) {
    int gid = blockIdx.x * 256 + threadIdx.x;  // 4096*256
    int b = gid >> 8, c = gid & 255;
    float a0 = 0.f, a1 = 0.f, a2 = 0.f, a3 = 0.f;
#pragma unroll
    for (int k = 0; k < 4; ++k) {
        float wk = w[b * 4 + k];
        ushort4 v = h2b[(long)(b * 4 + k) * 256 + c];
        a0 += wk * bf2f(v.x); a1 += wk * bf2f(v.y);
        a2 += wk * bf2f(v.z); a3 += wk * bf2f(v.w);
    }
    ushort4 o;
    o.x = f2bf(a0); o.y = f2bf(a1); o.z = f2bf(a2); o.w = f2bf(a3);
    fusedb[gid] = o;
}

__global__ __launch_bounds__(256) void fin2_kernel(const float* __restrict__ o,
                                                   const float* __restrict__ w2,
                                                   const float* __restrict__ b2,
                                                   float* __restrict__ out) {
    __shared__ float ws[512 * 20];
    int tid = threadIdx.x;
    for (int i = tid; i < 512 * 20; i += 256) ws[i] = w2[i];
    __syncthreads();
    int r = blockIdx.x * 64 + (tid >> 2);
    int c0 = (tid & 3) * 5;
    float acc[5];
#pragma unroll
    for (int j = 0; j < 5; ++j) acc[j] = b2[c0 + j];
    const float* orow = o + (long)r * 512;
    for (int i = 0; i < 512; ++i) {
        float v = orow[i];
#pragma unroll
        for (int j = 0; j < 5; ++j) acc[j] += v * ws[i * 20 + c0 + j];
    }
#pragma unroll
    for (int j = 0; j < 5; ++j) out[r * 20 + c0 + j] = acc[j];
}

extern "C" void kernel_launch(void* const* d_in, const int* in_sizes, int n_in,
                              void* d_out, int out_size, void* d_ws, size_t ws_size,
                              hipStream_t stream) {
    const float* wifi    = (const float*)d_in[0];
    const float* rfid    = (const float*)d_in[1];
    const float* gate_w1 = (const float*)d_in[2];
    const float* gate_b1 = (const float*)d_in[3];
    const float* gln_g   = (const float*)d_in[4];
    const float* gln_b   = (const float*)d_in[5];
    const float* gate_w2 = (const float*)d_in[6];
    const float* gate_b2 = (const float*)d_in[7];
    const float* exp_w1  = (const float*)d_in[8];
    const float* exp_b1  = (const float*)d_in[9];
    const float* bn1g    = (const float*)d_in[10];
    const float* bn1b    = (const float*)d_in[11];
    const float* bn1m    = (const float*)d_in[12];
    const float* bn1v    = (const float*)d_in[13];
    const float* exp_w2  = (const float*)d_in[14];
    const float* exp_b2  = (const float*)d_in[15];
    const float* bn2g    = (const float*)d_in[16];
    const float* bn2b    = (const float*)d_in[17];
    const float* bn2m    = (const float*)d_in[18];
    const float* bn2v    = (const float*)d_in[19];
    const float* fin_w1  = (const float*)d_in[20];
    const float* fin_b1  = (const float*)d_in[21];
    const float* fbng    = (const float*)d_in[22];
    const float* fbnb    = (const float*)d_in[23];
    const float* fbnm    = (const float*)d_in[24];
    const float* fbnv    = (const float*)d_in[25];
    const float* fin_w2  = (const float*)d_in[26];
    const float* fin_b2  = (const float*)d_in[27];
    float* out = (float*)d_out;

    const size_t MBy = 1u << 20;
    char* W = (char*)d_ws;
    float*          combined = (float*)         (W + 0);
    unsigned short* cbf      = (unsigned short*)(W + 8 * MBy);
    unsigned short* w1t      = (unsigned short*)(W + 12 * MBy);
    unsigned short* fusedb   = (unsigned short*)(W + 12 * MBy);   // after w1t dead
    float*          obuf     = (float*)         (W + 20 * MBy);   // after w1t dead
    unsigned short* w2t      = (unsigned short*)(W + 29 * MBy);
    float*          wq       = (float*)         (W + 61 * MBy);
    int*            rows     = (int*)           (W + 61 * MBy + (1 << 16));
    int*            counts   = (int*)           (W + 61 * MBy + (1 << 16) + (1 << 18));
    int*            wl       = (int*)           (W + 61 * MBy + (1 << 16) + (1 << 18) + 256);
    unsigned short* fw1t     = (unsigned short*)(W + 63 * MBy);
    unsigned short* h1bf     = (unsigned short*)(W + 65 * MBy);
    float*          gbuf     = (float*)         (W + 99 * MBy);
    unsigned short* h2b      = (unsigned short*)(W + 99 * MBy);   // after gbuf dead

    hipMemsetAsync(counts, 0, 16 * sizeof(int), stream);

    concat_kernel<<<2048, 256, 0, stream>>>((const float4*)wifi, (const float4*)rfid,
                                            (float4*)combined, (ushort4*)cbf);

    // weight transposes fp32 [K][N] -> bf16 [N][K]
    transpose_f2b<<<dim3(16, 8, 16), 256, 0, stream>>>(exp_w1, w1t, 512, 1024);
    transpose_f2b<<<dim3(16, 16, 16), 256, 0, stream>>>(exp_w2, w2t, 1024, 1024);
    transpose_f2b<<<dim3(8, 16, 1), 256, 0, stream>>>(fin_w1, fw1t, 1024, 512);

    // gate (fp32): GEMM1 -> fused LN/GELU/logits/softmax/top4 -> worklist
    gate_gemm<<<dim3(16, 32, 1), 256, 0, stream>>>(combined, 512, gate_w1, gate_b1,
                                                   gbuf, 1024, 1024, 512);
    ln_topk_kernel<<<4096, 256, 0, stream>>>(gbuf, gln_g, gln_b, gate_w2, gate_b2,
                                             wq, rows, counts);
    build_wl_kernel<<<1, 256, 0, stream>>>(counts, wl);

    // expert GEMM1 (worklist, bf16 MFMA): cbf rows -> h1bf[slot]
    mfma_gemm<64, 2, true, true, true><<<dim3(8, WL_MAX, 1), 256, 0, stream>>>(
        cbf, 512, w1t, (long)512 * 1024, exp_b1,
        bn1g, bn1b, bn1m, bn1v, 1024,
        h1bf, 1024, rows, counts, wl, 4096);

    // expert GEMM2 (worklist, bf16 MFMA): h1bf[slot] -> h2b[slot]
    mfma_gemm<64, 0, true, true, true><<<dim3(8, WL_MAX, 1), 256, 0, stream>>>(
        h1bf, 1024, w2t, (long)1024 * 1024, exp_b2,
        bn2g, bn2b, bn2m, bn2v, 1024,
        h2b, 1024, rows, counts, wl, 4096);

    combine_bf_kernel<<<4096, 256, 0, stream>>>((const ushort4*)h2b, wq, (ushort4*)fusedb);

    // final GEMM1 (dense, bf16 MFMA, TM=64 -> 256 blocks): fusedb -> obuf fp32
    mfma_gemm<64, 0, false, false, false><<<dim3(4, 1, 64), 256, 0, stream>>>(
        fusedb, 1024, fw1t, 0, fin_b1,
        fbng, fbnb, fbnm, fbnv, 0,
        obuf, 512, nullptr, counts, nullptr, 4096);

    fin2_kernel<<<64, 256, 0, stream>>>(obuf, fin_w2, fin_b2, out);
}

// Round 8
// 498.257 us; speedup vs baseline: 2.6573x; 1.0063x over previous
//
#include <hip/hip_runtime.h>

// MoE_77644418777543 — round 6 (resubmit; r7 bench was an infra failure).
// r6 post-mortem: worklist+TM=64 worked (111->88us, occ 40%, WRITE 32MB) but
// K-loop still barrier-bound: 8 MFMA/wave per vmcnt(0) drain, 32 barriers,
// and 8-way ds_read_b128 bank conflicts (6.6e6/dispatch).
// This round: BK=64 (16 barriers, 16 MFMA/wave/barrier, 24KB in flight) and
// k-chunk XOR swizzle kc^(row&7) -> 2-way conflicts (free, m136).
//
// Workspace (MB = 2^20), aliased by liveness:
//   0-8M    combined fp32            (gate gemm; then dead)
//   8-12M   cbf bf16                 (dead after expert GEMM1)
//   12-28M  w1t bf16 [16][1024][512] (dead after GEMM1) / fusedb@12M, obuf@20M after
//   29-61M  w2t bf16 [16][1024][1024](dead after GEMM2)
//   61M     wq / rows / counts / worklist
//   63-64M  fw1t bf16 [512][1024]
//   65-97M  h1bf bf16 [16384][1024]
//   99-131M gbuf fp32 (dead after ln_topk) then h2b bf16 [16384][1024]

#define EPSN 1e-5f

typedef __attribute__((ext_vector_type(8))) short v8s;   // 8 bf16 (4 VGPRs)
typedef __attribute__((ext_vector_type(4))) float v4f;   // 4 fp32 acc

typedef const unsigned int __attribute__((address_space(1)))* gas_u32;
typedef unsigned int __attribute__((address_space(3)))* las_u32;

__device__ __forceinline__ void glds16(const void* g, const void* l) {
    __builtin_amdgcn_global_load_lds((gas_u32)(uintptr_t)g, (las_u32)(uintptr_t)l, 16, 0, 0);
}

__device__ __forceinline__ float gelu_f(float x) {
    return 0.5f * x * (1.0f + erff(x * 0.70710678118654752440f));
}
__device__ __forceinline__ unsigned short f2bf(float x) {
    unsigned int u = __float_as_uint(x);
    u += 0x7fffu + ((u >> 16) & 1u);
    return (unsigned short)(u >> 16);
}
__device__ __forceinline__ float bf2f(unsigned short u) {
    return __uint_as_float(((unsigned int)u) << 16);
}

// concat wifi|rfid -> combined fp32, and also emit bf16 copy for MFMA path
__global__ __launch_bounds__(256) void concat_kernel(const float4* __restrict__ wifi,
                                                     const float4* __restrict__ rfid,
                                                     float4* __restrict__ comb,
                                                     ushort4* __restrict__ cbf) {
    int gid = blockIdx.x * 256 + threadIdx.x;   // 4096 * 128
    int b = gid >> 7, c = gid & 127;
    float4 v = (c < 64) ? wifi[b * 64 + c] : rfid[b * 64 + (c - 64)];
    comb[gid] = v;
    ushort4 o;
    o.x = f2bf(v.x); o.y = f2bf(v.y); o.z = f2bf(v.z); o.w = f2bf(v.w);
    cbf[gid] = o;
}

// in: per-expert [K][N] fp32 -> out: per-expert [N][K] bf16 (transpose+convert)
__global__ __launch_bounds__(256) void transpose_f2b(const float* __restrict__ in,
                                                     unsigned short* __restrict__ out,
                                                     int K, int N) {
    __shared__ float t[64][65];
    int e = blockIdx.z;
    int n0 = blockIdx.x << 6, k0 = blockIdx.y << 6;
    const float* ie = in + (long)e * K * N;
    unsigned short* oe = out + (long)e * N * K;
    int tid = threadIdx.x;
    int rr = tid >> 4, cc = (tid & 15) << 2;
#pragma unroll
    for (int p = 0; p < 4; ++p) {
        int k = (p << 4) + rr;
        float4 v = *(const float4*)(ie + (long)(k0 + k) * N + n0 + cc);
        t[k][cc + 0] = v.x; t[k][cc + 1] = v.y; t[k][cc + 2] = v.z; t[k][cc + 3] = v.w;
    }
    __syncthreads();
    int n = tid >> 2, kq = (tid & 3) << 4;
    unsigned short u[16];
#pragma unroll
    for (int j = 0; j < 16; ++j) u[j] = f2bf(t[kq + j][n]);
    uint4* dst = (uint4*)(oe + (long)(n0 + n) * K + k0 + kq);
    dst[0] = ((const uint4*)u)[0];
    dst[1] = ((const uint4*)u)[1];
}

// fp32 gate GEMM: 128x64 tile, BK=16, 256 threads, 8x4/thread. +bias only.
__global__ __launch_bounds__(256) void gate_gemm(
    const float* __restrict__ A, int lda,
    const float* __restrict__ W,
    const float* __restrict__ bias,
    float* __restrict__ out, int ldo, int N, int K)
{
    const int m0 = blockIdx.y << 7;
    const int n0 = blockIdx.x << 6;
    __shared__ float As[16][132];
    __shared__ float Bs[16][68];
    const int tid = threadIdx.x;
    const int ty = tid >> 4, tx = tid & 15;

    const int arow = tid >> 1;
    const int akq  = (tid & 1) << 3;
    const float* Aptr = A + (long)(m0 + arow) * lda + akq;
    const int bkr = tid >> 4;
    const int bnq = (tid & 15) << 2;
    const float* Bptr = W + (long)bkr * N + n0 + bnq;

    float acc[8][4] = {};
    for (int k0 = 0; k0 < K; k0 += 16) {
        float4 a0 = *(const float4*)(Aptr + k0);
        float4 a1 = *(const float4*)(Aptr + k0 + 4);
        float4 bv = *(const float4*)(Bptr + (long)k0 * N);
        As[akq + 0][arow] = a0.x; As[akq + 1][arow] = a0.y;
        As[akq + 2][arow] = a0.z; As[akq + 3][arow] = a0.w;
        As[akq + 4][arow] = a1.x; As[akq + 5][arow] = a1.y;
        As[akq + 6][arow] = a1.z; As[akq + 7][arow] = a1.w;
        *(float4*)&Bs[bkr][bnq] = bv;
        __syncthreads();
#pragma unroll
        for (int kk = 0; kk < 16; ++kk) {
            float4 af0 = *(const float4*)&As[kk][ty << 3];
            float4 af1 = *(const float4*)&As[kk][(ty << 3) + 4];
            float4 bf = *(const float4*)&Bs[kk][tx << 2];
            const float a8[8] = {af0.x, af0.y, af0.z, af0.w, af1.x, af1.y, af1.z, af1.w};
            const float b4[4] = {bf.x, bf.y, bf.z, bf.w};
#pragma unroll
            for (int i = 0; i < 8; ++i)
#pragma unroll
                for (int j = 0; j < 4; ++j)
                    acc[i][j] = fmaf(a8[i], b4[j], acc[i][j]);
        }
        __syncthreads();
    }
#pragma unroll
    for (int i = 0; i < 8; ++i) {
        int r = m0 + (ty << 3) + i;
        int c0 = n0 + (tx << 2);
        float4 v;
        v.x = acc[i][0] + bias[c0 + 0];
        v.y = acc[i][1] + bias[c0 + 1];
        v.z = acc[i][2] + bias[c0 + 2];
        v.w = acc[i][3] + bias[c0 + 3];
        *(float4*)(out + (long)r * ldo + c0) = v;
    }
}

// Fused: LayerNorm+GELU (row of 1024) -> gate logits (16) -> softmax -> top4
// -> renorm softmax -> scatter (rows/counts/weights). One block per row.
__global__ __launch_bounds__(256) void ln_topk_kernel(
    const float* __restrict__ g,
    const float* __restrict__ lng, const float* __restrict__ lnb,
    const float* __restrict__ w2, const float* __restrict__ b2,
    float* __restrict__ wout, int* __restrict__ rows_, int* __restrict__ counts)
{
    __shared__ float gs[1024];
    __shared__ float red[16][17];
    __shared__ float rs[4], rq[4];
    const int b = blockIdx.x;
    const int tid = threadIdx.x;
    const int c = tid << 2;

    float4 v = *(const float4*)(g + (long)b * 1024 + c);
    float s = v.x + v.y + v.z + v.w;
    float q = v.x * v.x + v.y * v.y + v.z * v.z + v.w * v.w;
    for (int off = 32; off > 0; off >>= 1) {
        s += __shfl_down(s, off);
        q += __shfl_down(q, off);
    }
    int wid = tid >> 6;
    if ((tid & 63) == 0) { rs[wid] = s; rq[wid] = q; }
    __syncthreads();
    float S = rs[0] + rs[1] + rs[2] + rs[3];
    float Q = rq[0] + rq[1] + rq[2] + rq[3];
    float mu = S * (1.0f / 1024.0f);
    float var = Q * (1.0f / 1024.0f) - mu * mu;
    float rstd = rsqrtf(var + EPSN);
    gs[c + 0] = gelu_f((v.x - mu) * rstd * lng[c + 0] + lnb[c + 0]);
    gs[c + 1] = gelu_f((v.y - mu) * rstd * lng[c + 1] + lnb[c + 1]);
    gs[c + 2] = gelu_f((v.z - mu) * rstd * lng[c + 2] + lnb[c + 2]);
    gs[c + 3] = gelu_f((v.w - mu) * rstd * lng[c + 3] + lnb[c + 3]);
    __syncthreads();

    const int e = tid & 15, chunk = tid >> 4;
    float p = 0.f;
#pragma unroll 8
    for (int i = 0; i < 64; ++i) {
        int idx = (chunk << 6) + i;
        p = fmaf(gs[idx], w2[(idx << 4) + e], p);
    }
    red[chunk][e] = p;
    __syncthreads();

    if (tid < 64) {
        float logit = -1e30f;
        if (tid < 16) {
            logit = b2[tid];
#pragma unroll
            for (int cc = 0; cc < 16; ++cc) logit += red[cc][tid];
        }
        float m = logit;
#pragma unroll
        for (int mk = 8; mk >= 1; mk >>= 1) m = fmaxf(m, __shfl_xor(m, mk));
        float pe = (tid < 16) ? expf(logit - m) : 0.f;
        float Z = pe;
#pragma unroll
        for (int mk = 8; mk >= 1; mk >>= 1) Z += __shfl_xor(Z, mk);
        float prob = pe / Z;

        float cur = (tid < 16) ? prob : -1.f;
        const int myi = tid & 15;
        float tv0, tv1, tv2, tv3;
        int ti0, ti1, ti2, ti3;
#define ARGMAX16(TV, TI)                                                     \
        {   float vv = cur; int ii = myi;                                    \
            _Pragma("unroll")                                                \
            for (int mk = 8; mk >= 1; mk >>= 1) {                            \
                float ov = __shfl_xor(vv, mk); int oi = __shfl_xor(ii, mk);  \
                if (ov > vv || (ov == vv && oi < ii)) { vv = ov; ii = oi; }  \
            }                                                                \
            TV = vv; TI = ii;                                                \
            if (myi == ii) cur = -1.f;                                       \
        }
        ARGMAX16(tv0, ti0)
        ARGMAX16(tv1, ti1)
        ARGMAX16(tv2, ti2)
        ARGMAX16(tv3, ti3)
#undef ARGMAX16

        float q0 = 1.f;
        float q1 = expf(tv1 - tv0);
        float q2 = expf(tv2 - tv0);
        float q3 = expf(tv3 - tv0);
        float iZ2 = 1.f / (q0 + q1 + q2 + q3);
        if (tid < 4) {
            float wk = (tid == 0) ? q0 : (tid == 1) ? q1 : (tid == 2) ? q2 : q3;
            int   ee = (tid == 0) ? ti0 : (tid == 1) ? ti1 : (tid == 2) ? ti2 : ti3;
            wout[(b << 2) + tid] = wk * iZ2;
            int j = atomicAdd(&counts[ee], 1);
            rows_[(ee << 12) + j] = (b << 2) | tid;
        }
    }
}

// Build exact work list of (expert<<16 | m_chunk) for TM=64 tiles.
// Sum over experts of ceil(cnt/64) <= 271 (Sum cnt = 16384). Sentinel -1.
#define WL_MAX 272
__global__ __launch_bounds__(256) void build_wl_kernel(const int* __restrict__ counts,
                                                       int* __restrict__ wl) {
    int t = threadIdx.x;
    for (int i = t; i < WL_MAX; i += 256) wl[i] = -1;
    __syncthreads();
    if (t == 0) {
        int idx = 0;
        for (int e = 0; e < 16; ++e) {
            int nc = (counts[e] + 63) >> 6;
            for (int c = 0; c < nc; ++c) wl[idx++] = (e << 16) | c;
        }
    }
}

// bf16 MFMA GEMM: 64x128 tile, BK=64, 256 threads (4 waves 2x2), 16 MFMA/wave/iter.
// LDS stage: A [64][64] + B [128][64] bf16, rows 128B, k-chunk XOR swizzle:
//   chunk kc of row r stored at position kc^(r&7) -> ds_read_b128 is 2-way (free).
// glds16 dest is lane-contiguous; swizzle applied via SOURCE pointer (k-offset).
// WL: grid (x=n-chunk, y=work-item); !WL: grid (x=n-chunk, 1, z=m-chunk) dense.
// OUTBF epilogue: BN+GELU -> bf16 LDS tile -> vectorized 16B row stores.
template<int ASHIFT, bool GATHER, bool OUTBF, bool WL>
__global__ __launch_bounds__(256) void mfma_gemm(
    const unsigned short* __restrict__ A, int K,
    const unsigned short* __restrict__ Wt, long wstride,
    const float* __restrict__ bias,
    const float* __restrict__ bng, const float* __restrict__ bnb,
    const float* __restrict__ bnm, const float* __restrict__ bnv,
    int pstride,
    void* __restrict__ outv, int ldo,
    const int* __restrict__ rows_, const int* __restrict__ counts,
    const int* __restrict__ wl, int M)
{
    constexpr int TM = 64;
    int e, m0;
    if constexpr (WL) {
        int w = wl[blockIdx.y];
        if (w < 0) return;
        e = w >> 16;
        m0 = (w & 0xffff) << 6;
    } else {
        e = blockIdx.y;
        m0 = blockIdx.z * TM;
    }
    const int n0 = blockIdx.x << 7;
    const int cnt = GATHER ? counts[e] : M;

    constexpr int AB_USH = 64 * 64 + 128 * 64;          // 12288 ush = 24KB
    constexpr int OL_STRIDE = 136;                      // 272B rows (16B-aligned)
    constexpr int OL_USH = OUTBF ? TM * OL_STRIDE : 0;  // 8704 ush (reuses stage)
    constexpr int SM_USH = (OL_USH > AB_USH) ? OL_USH : AB_USH;
    __shared__ __align__(16) unsigned short smem[SM_USH];
    unsigned short* Als = smem;            // [64 rows][64 k] (swizzled chunks)
    unsigned short* Bls = smem + 64 * 64;  // [128 rows][64 k]
    __shared__ int rid[TM];
    __shared__ int ain[TM];

    const int tid = threadIdx.x;
    if (tid < TM) {
        int i = m0 + tid;
        int pk, ai;
        if (GATHER) {
            if (i < cnt) { pk = rows_[(e << 12) + i]; ai = pk >> ASHIFT; }
            else { pk = -1; ai = 0; }
        } else { pk = i; ai = i; }
        rid[tid] = pk;
        ain[tid] = ai;
    }
    __syncthreads();

    const int wave = tid >> 6, lane = tid & 63;
    const int wm = (wave >> 1) << 5, wn = (wave & 1) << 6;   // 2x2 waves: m 0/32, n 0/64
    const int lrow = lane & 15, kch = lane >> 4;
    const int wb = wave << 9;                                // per-wave stage base (ush)

    // staging source map: slot-local row srow=tid>>3, dest chunk pos spos=tid&7,
    // source chunk skc = spos ^ (srow&7)   [XOR swizzle]
    const int srow = tid >> 3, spos = tid & 7;
    const int skc8 = (spos ^ (srow & 7)) << 3;

    const unsigned short* apa = A + (long)ain[srow] * K + skc8;
    const unsigned short* apb = A + (long)ain[32 + srow] * K + skc8;
    const unsigned short* Wte = Wt + (long)e * wstride;
    const unsigned short* bp0 = Wte + (long)(n0 + srow) * K + skc8;
    const unsigned short* bp1 = Wte + (long)(n0 + 32 + srow) * K + skc8;
    const unsigned short* bp2 = Wte + (long)(n0 + 64 + srow) * K + skc8;
    const unsigned short* bp3 = Wte + (long)(n0 + 96 + srow) * K + skc8;

    v4f acc[2][4] = {};

    const int nk = K >> 6;
    for (int it = 0; it < nk; ++it) {
        glds16(apa, Als + wb);
        glds16(apb, Als + 2048 + wb);
        glds16(bp0, Bls + wb);
        glds16(bp1, Bls + 2048 + wb);
        glds16(bp2, Bls + 4096 + wb);
        glds16(bp3, Bls + 6144 + wb);
        apa += 64; apb += 64; bp0 += 64; bp1 += 64; bp2 += 64; bp3 += 64;
        __syncthreads();

#pragma unroll
        for (int s = 0; s < 2; ++s) {
            const int kc = (s << 2) | kch;
            v8s av[2], bv[4];
#pragma unroll
            for (int f = 0; f < 2; ++f) {
                const int row = wm + (f << 4) + lrow;
                av[f] = *(const v8s*)(Als + row * 64 + ((kc ^ (row & 7)) << 3));
            }
#pragma unroll
            for (int f = 0; f < 4; ++f) {
                const int row = wn + (f << 4) + lrow;
                bv[f] = *(const v8s*)(Bls + row * 64 + ((kc ^ (row & 7)) << 3));
            }
#pragma unroll
            for (int fi = 0; fi < 2; ++fi)
#pragma unroll
                for (int fj = 0; fj < 4; ++fj)
                    acc[fi][fj] = __builtin_amdgcn_mfma_f32_16x16x32_bf16(
                        av[fi], bv[fj], acc[fi][fj], 0, 0, 0);
        }
        __syncthreads();
    }

    // epilogue: C/D layout col=lane&15, row=(lane>>4)*4+reg
    if constexpr (OUTBF) {
        unsigned short* Ols = smem;   // stage buffers dead after final barrier
#pragma unroll
        for (int fj = 0; fj < 4; ++fj) {
            const int c = wn + (fj << 4) + lrow;
            const int pc = e * pstride + n0 + c;
            const float bs = bias[pc];
            const float sc = bng[pc] * rsqrtf(bnv[pc] + EPSN);
            const float mn = bnm[pc], bb = bnb[pc];
#pragma unroll
            for (int fi = 0; fi < 2; ++fi) {
#pragma unroll
                for (int r = 0; r < 4; ++r) {
                    const int lr = wm + (fi << 4) + (kch << 2) + r;
                    float x = acc[fi][fj][r] + bs;
                    x = (x - mn) * sc + bb;
                    x = gelu_f(x);
                    Ols[lr * OL_STRIDE + c] = f2bf(x);
                }
            }
        }
        __syncthreads();
        const int rl = tid >> 4;
        const int c8 = (tid & 15) << 3;
#pragma unroll
        for (int p = 0; p < TM / 16; ++p) {
            const int row = (p << 4) + rl;
            const int orow = rid[row];
            if (orow >= 0) {
                uint4 v = *(const uint4*)(Ols + row * OL_STRIDE + c8);
                *(uint4*)((unsigned short*)outv + (long)orow * ldo + n0 + c8) = v;
            }
        }
    } else {
#pragma unroll
        for (int fj = 0; fj < 4; ++fj) {
            const int c = n0 + wn + (fj << 4) + lrow;
            const int pc = e * pstride + c;
            const float bs = bias[pc];
            const float sc = bng[pc] * rsqrtf(bnv[pc] + EPSN);
            const float mn = bnm[pc], bb = bnb[pc];
#pragma unroll
            for (int fi = 0; fi < 2; ++fi) {
#pragma unroll
                for (int r = 0; r < 4; ++r) {
                    const int lr = wm + (fi << 4) + (kch << 2) + r;
                    const int orow = rid[lr];
                    if (orow < 0) continue;
                    float x = acc[fi][fj][r] + bs;
                    x = (x - mn) * sc + bb;
                    x = gelu_f(x);
                    ((float*)outv)[(long)orow * ldo + c] = x;
                }
            }
        }
    }
}

// weighted top-4 combine, bf16 in -> bf16 out
__global__ __launch_bounds__(256) void combine_bf_kernel(const ushort4* __restrict__ h2b,
                                                         const float* __restrict__ w,
                                                         ushort4* __restrict__ fusedb) {
    int gid = blockIdx.x * 256 + threadIdx.x;  // 4096*256
    int b = gid >> 8, c = gid & 255;
    float a0 = 0.f, a1 = 0.f, a2 = 0.f, a3 = 0.f;
#pragma unroll
    for (int k = 0; k < 4; ++k) {
        float wk = w[b * 4 + k];
        ushort4 v = h2b[(long)(b * 4 + k) * 256 + c];
        a0 += wk * bf2f(v.x); a1 += wk * bf2f(v.y);
        a2 += wk * bf2f(v.z); a3 += wk * bf2f(v.w);
    }
    ushort4 o;
    o.x = f2bf(a0); o.y = f2bf(a1); o.z = f2bf(a2); o.w = f2bf(a3);
    fusedb[gid] = o;
}

__global__ __launch_bounds__(256) void fin2_kernel(const float* __restrict__ o,
                                                   const float* __restrict__ w2,
                                                   const float* __restrict__ b2,
                                                   float* __restrict__ out) {
    __shared__ float ws[512 * 20];
    int tid = threadIdx.x;
    for (int i = tid; i < 512 * 20; i += 256) ws[i] = w2[i];
    __syncthreads();
    int r = blockIdx.x * 64 + (tid >> 2);
    int c0 = (tid & 3) * 5;
    float acc[5];
#pragma unroll
    for (int j = 0; j < 5; ++j) acc[j] = b2[c0 + j];
    const float* orow = o + (long)r * 512;
    for (int i = 0; i < 512; ++i) {
        float v = orow[i];
#pragma unroll
        for (int j = 0; j < 5; ++j) acc[j] += v * ws[i * 20 + c0 + j];
    }
#pragma unroll
    for (int j = 0; j < 5; ++j) out[r * 20 + c0 + j] = acc[j];
}

extern "C" void kernel_launch(void* const* d_in, const int* in_sizes, int n_in,
                              void* d_out, int out_size, void* d_ws, size_t ws_size,
                              hipStream_t stream) {
    const float* wifi    = (const float*)d_in[0];
    const float* rfid    = (const float*)d_in[1];
    const float* gate_w1 = (const float*)d_in[2];
    const float* gate_b1 = (const float*)d_in[3];
    const float* gln_g   = (const float*)d_in[4];
    const float* gln_b   = (const float*)d_in[5];
    const float* gate_w2 = (const float*)d_in[6];
    const float* gate_b2 = (const float*)d_in[7];
    const float* exp_w1  = (const float*)d_in[8];
    const float* exp_b1  = (const float*)d_in[9];
    const float* bn1g    = (const float*)d_in[10];
    const float* bn1b    = (const float*)d_in[11];
    const float* bn1m    = (const float*)d_in[12];
    const float* bn1v    = (const float*)d_in[13];
    const float* exp_w2  = (const float*)d_in[14];
    const float* exp_b2  = (const float*)d_in[15];
    const float* bn2g    = (const float*)d_in[16];
    const float* bn2b    = (const float*)d_in[17];
    const float* bn2m    = (const float*)d_in[18];
    const float* bn2v    = (const float*)d_in[19];
    const float* fin_w1  = (const float*)d_in[20];
    const float* fin_b1  = (const float*)d_in[21];
    const float* fbng    = (const float*)d_in[22];
    const float* fbnb    = (const float*)d_in[23];
    const float* fbnm    = (const float*)d_in[24];
    const float* fbnv    = (const float*)d_in[25];
    const float* fin_w2  = (const float*)d_in[26];
    const float* fin_b2  = (const float*)d_in[27];
    float* out = (float*)d_out;

    const size_t MBy = 1u << 20;
    char* W = (char*)d_ws;
    float*          combined = (float*)         (W + 0);
    unsigned short* cbf      = (unsigned short*)(W + 8 * MBy);
    unsigned short* w1t      = (unsigned short*)(W + 12 * MBy);
    unsigned short* fusedb   = (unsigned short*)(W + 12 * MBy);   // after w1t dead
    float*          obuf     = (float*)         (W + 20 * MBy);   // after w1t dead
    unsigned short* w2t      = (unsigned short*)(W + 29 * MBy);
    float*          wq       = (float*)         (W + 61 * MBy);
    int*            rows     = (int*)           (W + 61 * MBy + (1 << 16));
    int*            counts   = (int*)           (W + 61 * MBy + (1 << 16) + (1 << 18));
    int*            wl       = (int*)           (W + 61 * MBy + (1 << 16) + (1 << 18) + 256);
    unsigned short* fw1t     = (unsigned short*)(W + 63 * MBy);
    unsigned short* h1bf     = (unsigned short*)(W + 65 * MBy);
    float*          gbuf     = (float*)         (W + 99 * MBy);
    unsigned short* h2b      = (unsigned short*)(W + 99 * MBy);   // after gbuf dead

    hipMemsetAsync(counts, 0, 16 * sizeof(int), stream);

    concat_kernel<<<2048, 256, 0, stream>>>((const float4*)wifi, (const float4*)rfid,
                                            (float4*)combined, (ushort4*)cbf);

    // weight transposes fp32 [K][N] -> bf16 [N][K]
    transpose_f2b<<<dim3(16, 8, 16), 256, 0, stream>>>(exp_w1, w1t, 512, 1024);
    transpose_f2b<<<dim3(16, 16, 16), 256, 0, stream>>>(exp_w2, w2t, 1024, 1024);
    transpose_f2b<<<dim3(8, 16, 1), 256, 0, stream>>>(fin_w1, fw1t, 1024, 512);

    // gate (fp32): GEMM1 -> fused LN/GELU/logits/softmax/top4 -> worklist
    gate_gemm<<<dim3(16, 32, 1), 256, 0, stream>>>(combined, 512, gate_w1, gate_b1,
                                                   gbuf, 1024, 1024, 512);
    ln_topk_kernel<<<4096, 256, 0, stream>>>(gbuf, gln_g, gln_b, gate_w2, gate_b2,
                                             wq, rows, counts);
    build_wl_kernel<<<1, 256, 0, stream>>>(counts, wl);

    // expert GEMM1 (worklist, bf16 MFMA, K=512): cbf rows -> h1bf[slot]
    mfma_gemm<2, true, true, true><<<dim3(8, WL_MAX, 1), 256, 0, stream>>>(
        cbf, 512, w1t, (long)512 * 1024, exp_b1,
        bn1g, bn1b, bn1m, bn1v, 1024,
        h1bf, 1024, rows, counts, wl, 4096);

    // expert GEMM2 (worklist, bf16 MFMA, K=1024): h1bf[slot] -> h2b[slot]
    mfma_gemm<0, true, true, true><<<dim3(8, WL_MAX, 1), 256, 0, stream>>>(
        h1bf, 1024, w2t, (long)1024 * 1024, exp_b2,
        bn2g, bn2b, bn2m, bn2v, 1024,
        h2b, 1024, rows, counts, wl, 4096);

    combine_bf_kernel<<<4096, 256, 0, stream>>>((const ushort4*)h2b, wq, (ushort4*)fusedb);

    // final GEMM1 (dense, bf16 MFMA, 256 blocks): fusedb -> obuf fp32, BN+GELU
    mfma_gemm<0, false, false, false><<<dim3(4, 1, 64), 256, 0, stream>>>(
        fusedb, 1024, fw1t, 0, fin_b1,
        fbng, fbnb, fbnm, fbnv, 0,
        obuf, 512, nullptr, counts, nullptr, 4096);

    fin2_kernel<<<64, 256, 0, stream>>>(obuf, fin_w2, fin_b2, out);
}